// Round 5
// baseline (1133.658 us; speedup 1.0000x reference)
//
#include <hip/hip_runtime.h>
#include <math.h>

// Problem constants
#define B_    8192
#define DIN_  1024
#define HID_  2048
#define LAT_  256
#define KC_   4096   // codebook size

using bfrag8 = __attribute__((ext_vector_type(8))) short;   // 8 bf16 (4 VGPR)
using short8 = __attribute__((ext_vector_type(8))) short;
using half8  = __attribute__((ext_vector_type(8))) _Float16;
using facc4  = __attribute__((ext_vector_type(4))) float;   // MFMA C/D frag

__device__ __forceinline__ unsigned short f2bf(float f) {
    union { float f; unsigned int u; } c; c.f = f;
    unsigned int u = c.u;
    return (unsigned short)((u + 0x7FFFu + ((u >> 16) & 1u)) >> 16);   // RNE
}

__device__ __forceinline__ unsigned short f2h_bits(float f) {
    union { _Float16 h; unsigned short u; } c; c.h = (_Float16)f;
    return c.u;
}

// Async global->LDS, 16B per lane. LDS dest is wave-uniform base + lane*16.
__device__ __forceinline__ void gload16(const unsigned short* g, unsigned short* l) {
    __builtin_amdgcn_global_load_lds(
        (const __attribute__((address_space(1))) void*)(g),
        (__attribute__((address_space(3))) void*)(l), 16, 0, 0);
}

// ---------------------------------------------------------------------------
// Encoder GEMM, 8-wave variant: 128x128 block, 512 threads, wave grid 2m x 4n,
// wave tile 64x32 (per-wave regs/chains IDENTICAL to the verified 4-wave
// kernel -> bit-identical outputs). A-tile LDS reuse x2, 16 waves/CU.
// OUT_SPLIT: 0 = f32 only, 1 = f16 split only, 2 = f32 + f16 split.
// ---------------------------------------------------------------------------
template <int GELU, int OUT_SPLIT>
__global__ __launch_bounds__(512, 4) void gemm_split_f16_w8(
    const unsigned short* __restrict__ Ahi, const unsigned short* __restrict__ Alo,
    const unsigned short* __restrict__ WThi, const unsigned short* __restrict__ WTlo,
    const float* __restrict__ bias,
    unsigned short* __restrict__ Chi, unsigned short* __restrict__ Clo,
    float* __restrict__ Cf32,
    int M, int N, int K)
{
    __shared__ __align__(16) unsigned short AsH[128 * 64];   // 16 KB
    __shared__ __align__(16) unsigned short AsL[128 * 64];   // 16 KB
    __shared__ __align__(16) unsigned short WsH[128 * 64];   // 16 KB
    __shared__ __align__(16) unsigned short WsL[128 * 64];   // 16 KB

    const int tid  = threadIdx.x;
    const int wave = tid >> 6;
    const int lane = tid & 63;
    const int wm   = wave & 1;        // wave row (2x4 wave grid)
    const int wn   = wave >> 1;       // wave col 0..3
    const int quad = lane >> 4;
    const int ln   = lane & 15;
    const int n0 = blockIdx.x * 128;  // x = n-tile: consecutive blocks share A (L2)
    const int m0 = blockIdx.y * 128;

    const facc4 fz4 = {0.0f, 0.0f, 0.0f, 0.0f};
    facc4 accA[4][2] = {};    // hi*hi, scale 64, reset every 256 k
    facc4 accB[4][2] = {};    // hi*lo + lo*hi, scale 64*4096, full-K chain
    facc4 master[4][2] = {};  // blocked sum of accA

    for (int k0 = 0; k0 < K; k0 += 64) {
        // stage A tile 128x64 (hi+lo): 1024 granules / 512 threads = 2 iters
#pragma unroll
        for (int i = 0; i < 2; ++i) {
            const int idx = i * 512 + tid;
            const int row = idx >> 3;
            const int gs  = (idx & 7) ^ (row & 7);
            const int wb  = i * 512 + (tid & 448);     // wave-uniform granule base
            const size_t src = (size_t)(m0 + row) * K + k0 + gs * 8;
            gload16(&Ahi[src], &AsH[wb * 8]);
            gload16(&Alo[src], &AsL[wb * 8]);
        }
        // stage W tile 128x64 (hi+lo)
#pragma unroll
        for (int i = 0; i < 2; ++i) {
            const int idx = i * 512 + tid;
            const int row = idx >> 3;
            const int gs  = (idx & 7) ^ (row & 7);
            const int wb  = i * 512 + (tid & 448);
            const size_t src = (size_t)(n0 + row) * K + k0 + gs * 8;
            gload16(&WThi[src], &WsH[wb * 8]);
            gload16(&WTlo[src], &WsL[wb * 8]);
        }
        __syncthreads();
#pragma unroll
        for (int ks = 0; ks < 64; ks += 32) {
            const int gq = (ks >> 3) + quad;      // source granule for this chunk
            half8 aH[4], aL[4], bH[2], bL[2];
#pragma unroll
            for (int f = 0; f < 4; ++f) {
                const int row = wm * 64 + f * 16 + ln;
                const int off = row * 64 + ((gq ^ (ln & 7)) << 3);
                aH[f] = *reinterpret_cast<const half8*>(&AsH[off]);
                aL[f] = *reinterpret_cast<const half8*>(&AsL[off]);
            }
#pragma unroll
            for (int f = 0; f < 2; ++f) {
                const int row = wn * 32 + f * 16 + ln;
                const int off = row * 64 + ((gq ^ (ln & 7)) << 3);
                bH[f] = *reinterpret_cast<const half8*>(&WsH[off]);
                bL[f] = *reinterpret_cast<const half8*>(&WsL[off]);
            }
#pragma unroll
            for (int fm = 0; fm < 4; ++fm)
#pragma unroll
                for (int fn = 0; fn < 2; ++fn)
                    accA[fm][fn] = __builtin_amdgcn_mfma_f32_16x16x32_f16(
                        aH[fm], bH[fn], accA[fm][fn], 0, 0, 0);
#pragma unroll
            for (int fm = 0; fm < 4; ++fm)
#pragma unroll
                for (int fn = 0; fn < 2; ++fn)
                    accB[fm][fn] = __builtin_amdgcn_mfma_f32_16x16x32_f16(
                        aH[fm], bL[fn], accB[fm][fn], 0, 0, 0);
#pragma unroll
            for (int fm = 0; fm < 4; ++fm)
#pragma unroll
                for (int fn = 0; fn < 2; ++fn)
                    accB[fm][fn] = __builtin_amdgcn_mfma_f32_16x16x32_f16(
                        aL[fm], bH[fn], accB[fm][fn], 0, 0, 0);
        }
        __syncthreads();
        if ((k0 & 192) == 192) {            // end of each 256-k block: promote
#pragma unroll
            for (int fm = 0; fm < 4; ++fm)
#pragma unroll
                for (int fn = 0; fn < 2; ++fn) {
                    master[fm][fn] += accA[fm][fn];
                    accA[fm][fn] = fz4;
                }
        }
    }

    const double SC_HI = 0.015625;               // 1/64
    const double SC_LO = 3.814697265625e-06;     // 1/(64*4096)
#pragma unroll
    for (int fn = 0; fn < 2; ++fn) {
        const int col = n0 + wn * 32 + fn * 16 + ln;
        const double bb = (double)bias[col];
#pragma unroll
        for (int fm = 0; fm < 4; ++fm) {
            const int rbase = m0 + wm * 64 + fm * 16 + quad * 4;
#pragma unroll
            for (int r = 0; r < 4; ++r) {
                double v = (double)master[fm][fn][r] * SC_HI
                         + (double)accB[fm][fn][r] * SC_LO + bb;
                if (GELU) v = 0.5 * v * (1.0 + erf(v * 0.70710678118654752440));
                const float hf = (float)v;
                if (OUT_SPLIT == 1 || OUT_SPLIT == 2) {
                    const _Float16 hi = (_Float16)hf;
                    const float lo = (hf - (float)hi) * 4096.0f;
                    union { _Float16 h; unsigned short u; } c1, c2;
                    c1.h = hi; c2.h = (_Float16)lo;
                    Chi[(size_t)(rbase + r) * N + col] = c1.u;
                    Clo[(size_t)(rbase + r) * N + col] = c2.u;
                }
                if (OUT_SPLIT == 0 || OUT_SPLIT == 2) {
                    Cf32[(size_t)(rbase + r) * N + col] = hf;
                }
            }
        }
    }
}

// ---------------------------------------------------------------------------
// Encoder GEMM, 4-wave 128x64 variant (verified rounds 1-4) — kept for enc3
// (N=256: the 128-wide variant would under-occupy the grid).
// ---------------------------------------------------------------------------
template <int GELU, int OUT_SPLIT>
__global__ __launch_bounds__(256, 3) void gemm_split_f16(
    const unsigned short* __restrict__ Ahi, const unsigned short* __restrict__ Alo,
    const unsigned short* __restrict__ WThi, const unsigned short* __restrict__ WTlo,
    const float* __restrict__ bias,
    unsigned short* __restrict__ Chi, unsigned short* __restrict__ Clo,
    float* __restrict__ Cf32,
    int M, int N, int K)
{
    __shared__ __align__(16) unsigned short AsH[128 * 64];   // 16 KB
    __shared__ __align__(16) unsigned short AsL[128 * 64];   // 16 KB
    __shared__ __align__(16) unsigned short WsH[64 * 64];    // 8 KB
    __shared__ __align__(16) unsigned short WsL[64 * 64];    // 8 KB

    const int tid  = threadIdx.x;
    const int wave = tid >> 6;
    const int lane = tid & 63;
    const int wm   = wave & 1;        // wave row (2x2 wave grid)
    const int wn   = wave >> 1;       // wave col
    const int quad = lane >> 4;
    const int ln   = lane & 15;
    const int n0 = blockIdx.x * 64;
    const int m0 = blockIdx.y * 128;

    const facc4 fz4 = {0.0f, 0.0f, 0.0f, 0.0f};
    facc4 accA[4][2] = {};
    facc4 accB[4][2] = {};
    facc4 master[4][2] = {};

    for (int k0 = 0; k0 < K; k0 += 64) {
#pragma unroll
        for (int i = 0; i < 4; ++i) {
            const int idx = i * 256 + tid;
            const int row = idx >> 3;
            const int gs  = (idx & 7) ^ (row & 7);
            const int wb  = i * 256 + (tid & 192);
            const size_t src = (size_t)(m0 + row) * K + k0 + gs * 8;
            gload16(&Ahi[src], &AsH[wb * 8]);
            gload16(&Alo[src], &AsL[wb * 8]);
        }
#pragma unroll
        for (int i = 0; i < 2; ++i) {
            const int idx = i * 256 + tid;
            const int row = idx >> 3;
            const int gs  = (idx & 7) ^ (row & 7);
            const int wb  = i * 256 + (tid & 192);
            const size_t src = (size_t)(n0 + row) * K + k0 + gs * 8;
            gload16(&WThi[src], &WsH[wb * 8]);
            gload16(&WTlo[src], &WsL[wb * 8]);
        }
        __syncthreads();
#pragma unroll
        for (int ks = 0; ks < 64; ks += 32) {
            const int gq = (ks >> 3) + quad;
            half8 aH[4], aL[4], bH[2], bL[2];
#pragma unroll
            for (int f = 0; f < 4; ++f) {
                const int row = wm * 64 + f * 16 + ln;
                const int off = row * 64 + ((gq ^ (ln & 7)) << 3);
                aH[f] = *reinterpret_cast<const half8*>(&AsH[off]);
                aL[f] = *reinterpret_cast<const half8*>(&AsL[off]);
            }
#pragma unroll
            for (int f = 0; f < 2; ++f) {
                const int row = wn * 32 + f * 16 + ln;
                const int off = row * 64 + ((gq ^ (ln & 7)) << 3);
                bH[f] = *reinterpret_cast<const half8*>(&WsH[off]);
                bL[f] = *reinterpret_cast<const half8*>(&WsL[off]);
            }
#pragma unroll
            for (int fm = 0; fm < 4; ++fm)
#pragma unroll
                for (int fn = 0; fn < 2; ++fn)
                    accA[fm][fn] = __builtin_amdgcn_mfma_f32_16x16x32_f16(
                        aH[fm], bH[fn], accA[fm][fn], 0, 0, 0);
#pragma unroll
            for (int fm = 0; fm < 4; ++fm)
#pragma unroll
                for (int fn = 0; fn < 2; ++fn)
                    accB[fm][fn] = __builtin_amdgcn_mfma_f32_16x16x32_f16(
                        aH[fm], bL[fn], accB[fm][fn], 0, 0, 0);
#pragma unroll
            for (int fm = 0; fm < 4; ++fm)
#pragma unroll
                for (int fn = 0; fn < 2; ++fn)
                    accB[fm][fn] = __builtin_amdgcn_mfma_f32_16x16x32_f16(
                        aL[fm], bH[fn], accB[fm][fn], 0, 0, 0);
        }
        __syncthreads();
        if ((k0 & 192) == 192) {
#pragma unroll
            for (int fm = 0; fm < 4; ++fm)
#pragma unroll
                for (int fn = 0; fn < 2; ++fn) {
                    master[fm][fn] += accA[fm][fn];
                    accA[fm][fn] = fz4;
                }
        }
    }

    const double SC_HI = 0.015625;               // 1/64
    const double SC_LO = 3.814697265625e-06;     // 1/(64*4096)
#pragma unroll
    for (int fn = 0; fn < 2; ++fn) {
        const int col = n0 + wn * 32 + fn * 16 + ln;
        const double bb = (double)bias[col];
#pragma unroll
        for (int fm = 0; fm < 4; ++fm) {
            const int rbase = m0 + wm * 64 + fm * 16 + quad * 4;
#pragma unroll
            for (int r = 0; r < 4; ++r) {
                double v = (double)master[fm][fn][r] * SC_HI
                         + (double)accB[fm][fn][r] * SC_LO + bb;
                if (GELU) v = 0.5 * v * (1.0 + erf(v * 0.70710678118654752440));
                const float hf = (float)v;
                if (OUT_SPLIT == 1 || OUT_SPLIT == 2) {
                    const _Float16 hi = (_Float16)hf;
                    const float lo = (hf - (float)hi) * 4096.0f;
                    union { _Float16 h; unsigned short u; } c1, c2;
                    c1.h = hi; c2.h = (_Float16)lo;
                    Chi[(size_t)(rbase + r) * N + col] = c1.u;
                    Clo[(size_t)(rbase + r) * N + col] = c2.u;
                }
                if (OUT_SPLIT == 0 || OUT_SPLIT == 2) {
                    Cf32[(size_t)(rbase + r) * N + col] = hf;
                }
            }
        }
    }
}

// ---------------------------------------------------------------------------
// Split fp32 -> (hi, lo*4096) fp16 pair, with pre-scale (power of two, exact).
// ---------------------------------------------------------------------------
__global__ __launch_bounds__(256) void split_scaled_f16x2(
    const float* __restrict__ X, unsigned short* __restrict__ Xhi,
    unsigned short* __restrict__ Xlo, int n4, float scale)
{
    const int i = blockIdx.x * 256 + threadIdx.x;
    if (i >= n4) return;
    const float4 v = reinterpret_cast<const float4*>(X)[i];
    ushort4 h, l;
    {
        const float s = v.x * scale;
        _Float16 a = (_Float16)s; h.x = f2h_bits((float)a); l.x = f2h_bits((s - (float)a) * 4096.0f);
    }
    {
        const float s = v.y * scale;
        _Float16 a = (_Float16)s; h.y = f2h_bits((float)a); l.y = f2h_bits((s - (float)a) * 4096.0f);
    }
    {
        const float s = v.z * scale;
        _Float16 a = (_Float16)s; h.z = f2h_bits((float)a); l.z = f2h_bits((s - (float)a) * 4096.0f);
    }
    {
        const float s = v.w * scale;
        _Float16 a = (_Float16)s; h.w = f2h_bits((float)a); l.w = f2h_bits((s - (float)a) * 4096.0f);
    }
    reinterpret_cast<ushort4*>(Xhi)[i] = h;
    reinterpret_cast<ushort4*>(Xlo)[i] = l;
}

// ---------------------------------------------------------------------------
// Fused codebook prep: esq + f16 split (x2^16) + loss zero. (verified r4)
// ---------------------------------------------------------------------------
__global__ __launch_bounds__(64) void emb_prep(
    const float* __restrict__ E, float* __restrict__ esq,
    unsigned short* __restrict__ Ehi, unsigned short* __restrict__ Elo,
    float* __restrict__ loss_slot)
{
    const int r = blockIdx.x;
    const float4 v = reinterpret_cast<const float4*>(E + (size_t)r * LAT_)[threadIdx.x];
    ushort4 h, l;
    {
        const float s = v.x * 65536.0f;
        _Float16 a = (_Float16)s; h.x = f2h_bits((float)a); l.x = f2h_bits((s - (float)a) * 4096.0f);
    }
    {
        const float s = v.y * 65536.0f;
        _Float16 a = (_Float16)s; h.y = f2h_bits((float)a); l.y = f2h_bits((s - (float)a) * 4096.0f);
    }
    {
        const float s = v.z * 65536.0f;
        _Float16 a = (_Float16)s; h.z = f2h_bits((float)a); l.z = f2h_bits((s - (float)a) * 4096.0f);
    }
    {
        const float s = v.w * 65536.0f;
        _Float16 a = (_Float16)s; h.w = f2h_bits((float)a); l.w = f2h_bits((s - (float)a) * 4096.0f);
    }
    reinterpret_cast<ushort4*>(Ehi + (size_t)r * LAT_)[threadIdx.x] = h;
    reinterpret_cast<ushort4*>(Elo + (size_t)r * LAT_)[threadIdx.x] = l;
    double s = (double)v.x * v.x + (double)v.y * v.y + (double)v.z * v.z + (double)v.w * v.w;
#pragma unroll
    for (int off = 32; off; off >>= 1) s += __shfl_down(s, off, 64);
    if (threadIdx.x == 0) {
        esq[r] = (float)s;
        if (r == 0) *loss_slot = 0.0f;
    }
}

// ---------------------------------------------------------------------------
// Weight prep: W [K,N] fp32 -> WThi/WTlo [N,K] f16 of (W*64, residual*4096).
// ---------------------------------------------------------------------------
__global__ __launch_bounds__(256) void wsplit_transpose(
    const float* __restrict__ W, unsigned short* __restrict__ WThi,
    unsigned short* __restrict__ WTlo, int K, int N)
{
    __shared__ float t[32][33];
    const int k0 = blockIdx.x * 32;
    const int n0 = blockIdx.y * 32;
    const int x = threadIdx.x;
    const int y = threadIdx.y;
#pragma unroll
    for (int i = 0; i < 4; ++i)
        t[y + i * 8][x] = W[(size_t)(k0 + y + i * 8) * N + n0 + x];
    __syncthreads();
#pragma unroll
    for (int i = 0; i < 4; ++i) {
        const float w = t[x][y + i * 8] * 64.0f;
        const _Float16 hi = (_Float16)w;
        const float lo = (w - (float)hi) * 4096.0f;
        WThi[(size_t)(n0 + y + i * 8) * K + k0 + x] = f2h_bits((float)hi);
        WTlo[(size_t)(n0 + y + i * 8) * K + k0 + x] = f2h_bits(lo);
    }
}

// ---------------------------------------------------------------------------
// VQ distance + argmin via fp16-split MFMA (verified round 4, unchanged).
// ---------------------------------------------------------------------------
__global__ __launch_bounds__(256, 2) void vq_argmin_mfma(
    const unsigned short* __restrict__ Zhi, const unsigned short* __restrict__ Zlo,
    const unsigned short* __restrict__ Ehi, const unsigned short* __restrict__ Elo,
    const float* __restrict__ esq, const float* __restrict__ zsq,
    float* __restrict__ pval, int* __restrict__ pidx)
{
    __shared__ __align__(16) unsigned short ZsH[128 * 64];   // 16 KB
    __shared__ __align__(16) unsigned short ZsL[128 * 64];   // 16 KB
    __shared__ __align__(16) unsigned short EsH[64 * 64];    // 8 KB
    __shared__ __align__(16) unsigned short EsL[64 * 64];    // 8 KB
    __shared__ float rbv[128][2];
    __shared__ int   rbi[128][2];

    const int tid  = threadIdx.x;
    const int wave = tid >> 6;
    const int lane = tid & 63;
    const int wm   = wave & 1;
    const int wn   = wave >> 1;
    const int quad = lane >> 4;
    const int ln   = lane & 15;
    const int m0    = blockIdx.x * 128;
    const int split = blockIdx.y;

    float zsqv[4][4];
#pragma unroll
    for (int fm = 0; fm < 4; ++fm) {
        const float4 q = *reinterpret_cast<const float4*>(
            &zsq[m0 + wm * 64 + fm * 16 + quad * 4]);
        zsqv[fm][0] = q.x; zsqv[fm][1] = q.y; zsqv[fm][2] = q.z; zsqv[fm][3] = q.w;
    }

    float bestv[4][4];
    int   besti[4][4];
#pragma unroll
    for (int a = 0; a < 4; ++a)
#pragma unroll
        for (int b = 0; b < 4; ++b) { bestv[a][b] = 3.4e38f; besti[a][b] = 0; }

    for (int nt = 0; nt < 8; ++nt) {
        const int n0 = split * 512 + nt * 64;
        facc4 accA[4][2] = {};
        facc4 accB[4][2] = {};
        for (int k0 = 0; k0 < 256; k0 += 64) {
            __syncthreads();
#pragma unroll
            for (int i = 0; i < 4; ++i) {
                const int idx = i * 256 + tid;
                const int row = idx >> 3;
                const int gs  = (idx & 7) ^ (row & 7);
                const int wb  = i * 256 + (tid & 192);
                const size_t src = (size_t)(m0 + row) * LAT_ + k0 + gs * 8;
                gload16(&Zhi[src], &ZsH[wb * 8]);
                gload16(&Zlo[src], &ZsL[wb * 8]);
            }
#pragma unroll
            for (int i = 0; i < 2; ++i) {
                const int idx = i * 256 + tid;
                const int row = idx >> 3;
                const int gs  = (idx & 7) ^ (row & 7);
                const int wb  = i * 256 + (tid & 192);
                const size_t src = (size_t)(n0 + row) * LAT_ + k0 + gs * 8;
                gload16(&Ehi[src], &EsH[wb * 8]);
                gload16(&Elo[src], &EsL[wb * 8]);
            }
            __syncthreads();
#pragma unroll
            for (int ks = 0; ks < 64; ks += 32) {
                const int gq = (ks >> 3) + quad;
                half8 aH[4], aL[4], bH[2], bL[2];
#pragma unroll
                for (int f = 0; f < 4; ++f) {
                    const int row = wm * 64 + f * 16 + ln;
                    const int off = row * 64 + ((gq ^ (ln & 7)) << 3);
                    aH[f] = *reinterpret_cast<const half8*>(&ZsH[off]);
                    aL[f] = *reinterpret_cast<const half8*>(&ZsL[off]);
                }
#pragma unroll
                for (int f = 0; f < 2; ++f) {
                    const int row = wn * 32 + f * 16 + ln;
                    const int off = row * 64 + ((gq ^ (ln & 7)) << 3);
                    bH[f] = *reinterpret_cast<const half8*>(&EsH[off]);
                    bL[f] = *reinterpret_cast<const half8*>(&EsL[off]);
                }
#pragma unroll
                for (int fm = 0; fm < 4; ++fm)
#pragma unroll
                    for (int fn = 0; fn < 2; ++fn)
                        accA[fm][fn] = __builtin_amdgcn_mfma_f32_16x16x32_f16(
                            aH[fm], bH[fn], accA[fm][fn], 0, 0, 0);
#pragma unroll
                for (int fm = 0; fm < 4; ++fm)
#pragma unroll
                    for (int fn = 0; fn < 2; ++fn)
                        accB[fm][fn] = __builtin_amdgcn_mfma_f32_16x16x32_f16(
                            aH[fm], bL[fn], accB[fm][fn], 0, 0, 0);
#pragma unroll
                for (int fm = 0; fm < 4; ++fm)
#pragma unroll
                    for (int fn = 0; fn < 2; ++fn)
                        accB[fm][fn] = __builtin_amdgcn_mfma_f32_16x16x32_f16(
                            aL[fm], bH[fn], accB[fm][fn], 0, 0, 0);
            }
        }
#pragma unroll
        for (int fm = 0; fm < 4; ++fm)
#pragma unroll
            for (int fn = 0; fn < 2; ++fn) {
                const int n = n0 + wn * 32 + fn * 16 + ln;
                const float es = esq[n];
#pragma unroll
                for (int r = 0; r < 4; ++r) {
                    const float pa = accA[fm][fn][r] * 0x1p-15f;   // exact
                    const float pb = accB[fm][fn][r] * 0x1p-27f;   // exact
                    const float t2m = pa + pb;
                    const float sc = (zsqv[fm][r] + es) - t2m;
                    if (sc < bestv[fm][r]) { bestv[fm][r] = sc; besti[fm][r] = n; }
                }
            }
    }

#pragma unroll
    for (int fm = 0; fm < 4; ++fm)
#pragma unroll
        for (int r = 0; r < 4; ++r) {
            float v0 = bestv[fm][r]; int i0 = besti[fm][r];
#pragma unroll
            for (int mask = 1; mask < 16; mask <<= 1) {
                const float v2 = __shfl_xor(v0, mask, 64);
                const int   i2 = __shfl_xor(i0, mask, 64);
                if (v2 < v0 || (v2 == v0 && i2 < i0)) { v0 = v2; i0 = i2; }
            }
            bestv[fm][r] = v0; besti[fm][r] = i0;
        }

    if (ln == 0) {
#pragma unroll
        for (int fm = 0; fm < 4; ++fm)
#pragma unroll
            for (int r = 0; r < 4; ++r) {
                const int rl = wm * 64 + fm * 16 + quad * 4 + r;
                rbv[rl][wn] = bestv[fm][r];
                rbi[rl][wn] = besti[fm][r];
            }
    }
    __syncthreads();
    if (tid < 128) {
        float bv = rbv[tid][0]; int bi = rbi[tid][0];
        const float v = rbv[tid][1]; const int ix = rbi[tid][1];
        if (v < bv || (v == bv && ix < bi)) { bv = v; bi = ix; }
        pval[(size_t)(m0 + tid) * 8 + split] = bv;
        pidx[(m0 + tid) * 8 + split] = bi;
    }
}

// ---------------------------------------------------------------------------
// Decoder GEMM: bf16 MFMA 16x16x32 (verified, unchanged)
// ---------------------------------------------------------------------------
template <int OUT_BF16>
__global__ __launch_bounds__(256) void gemm_mfma_bf16(
    const unsigned short* __restrict__ A,
    const unsigned short* __restrict__ WT,
    const float* __restrict__ bias,
    void* __restrict__ Cout,
    int M, int N, int K)
{
    __shared__ __align__(16) unsigned short As[128 * 64];   // [m][k], 16 KB
    __shared__ __align__(16) unsigned short Bs[128 * 64];   // [n][k], 16 KB

    const int tid  = threadIdx.x;
    const int wave = tid >> 6;
    const int lane = tid & 63;
    const int wm   = wave & 1;
    const int wn   = wave >> 1;
    const int quad = lane >> 4;
    const int ln   = lane & 15;
    const int m0 = blockIdx.x * 128;
    const int n0 = blockIdx.y * 128;

    facc4 acc[4][4] = {};

    for (int k0 = 0; k0 < K; k0 += 64) {
#pragma unroll
        for (int i = 0; i < 4; ++i) {
            const int idx = i * 256 + tid;
            const int row = idx >> 3;
            const int c8  = (idx & 7) * 8;
            const int wb  = i * 256 + (tid & 192);
            gload16(&A[(size_t)(m0 + row) * K + k0 + c8], &As[wb * 8]);
            gload16(&WT[(size_t)(n0 + row) * K + k0 + c8], &Bs[wb * 8]);
        }
        __syncthreads();
#pragma unroll
        for (int ks = 0; ks < 64; ks += 32) {
            bfrag8 am[4], bn[4];
#pragma unroll
            for (int f = 0; f < 4; ++f) {
                am[f] = *reinterpret_cast<const bfrag8*>(
                    &As[(wm * 64 + f * 16 + ln) * 64 + ks + quad * 8]);
                bn[f] = *reinterpret_cast<const bfrag8*>(
                    &Bs[(wn * 64 + f * 16 + ln) * 64 + ks + quad * 8]);
            }
#pragma unroll
            for (int fm = 0; fm < 4; ++fm)
#pragma unroll
                for (int fn = 0; fn < 4; ++fn)
                    acc[fm][fn] = __builtin_amdgcn_mfma_f32_16x16x32_bf16(
                        am[fm], bn[fn], acc[fm][fn], 0, 0, 0);
        }
        __syncthreads();
    }

#pragma unroll
    for (int fn = 0; fn < 4; ++fn) {
        const int col = n0 + wn * 64 + fn * 16 + ln;
        const float bf = bias[col];
#pragma unroll
        for (int fm = 0; fm < 4; ++fm) {
            const int rbase = m0 + wm * 64 + fm * 16 + quad * 4;
#pragma unroll
            for (int r = 0; r < 4; ++r) {
                float v = acc[fm][fn][r] + bf;
                if (OUT_BF16) {
                    v = 0.5f * v * (1.0f + erff(v * 0.70710678118654752440f));
                    ((unsigned short*)Cout)[(size_t)(rbase + r) * N + col] = f2bf(v);
                } else {
                    ((float*)Cout)[(size_t)(rbase + r) * N + col] = v;
                }
            }
        }
    }
}

// ---------------------------------------------------------------------------
// Fused cast+transpose for the three decoder weights (bit-identical per-tile
// math to cast_transpose_w; one dispatch instead of three).
//   D1 [256,2048]:  512 tiles   (kt 8,  nt 64)
//   D2 [2048,2048]: 4096 tiles  (kt 64, nt 64)
//   D3 [2048,1024]: 2048 tiles  (kt 64, nt 32)
// ---------------------------------------------------------------------------
__global__ __launch_bounds__(256) void cast_transpose_w3(
    const float* __restrict__ D1w, unsigned short* __restrict__ wt1,
    const float* __restrict__ D2w, unsigned short* __restrict__ wt2,
    const float* __restrict__ D3w, unsigned short* __restrict__ wt3)
{
    const int bid = blockIdx.x;
    const float* W; unsigned short* WT; int K, N, kt, nt;
    if (bid < 512)        { W = D1w; WT = wt1; K = LAT_; N = HID_; kt = bid & 7;  nt = bid >> 3; }
    else if (bid < 4608)  { const int l = bid - 512;  W = D2w; WT = wt2; K = HID_; N = HID_; kt = l & 63; nt = l >> 6; }
    else                  { const int l = bid - 4608; W = D3w; WT = wt3; K = HID_; N = DIN_; kt = l & 63; nt = l >> 6; }

    __shared__ float t[32][33];
    const int k0 = kt * 32;
    const int n0 = nt * 32;
    const int x = threadIdx.x;
    const int y = threadIdx.y;
#pragma unroll
    for (int i = 0; i < 4; ++i)
        t[y + i * 8][x] = W[(size_t)(k0 + y + i * 8) * N + n0 + x];
    __syncthreads();
#pragma unroll
    for (int i = 0; i < 4; ++i)
        WT[(size_t)(n0 + y + i * 8) * K + k0 + x] = f2bf(t[x][y + i * 8]);
}

// ---------------------------------------------------------------------------
// rowsq[r] = fp32( fp64 sum of X[r,:].^2 ), rows of width LAT_=256.
// ---------------------------------------------------------------------------
__global__ __launch_bounds__(64) void rowsq_kernel(
    const float* __restrict__ X, float* __restrict__ out,
    float* __restrict__ loss_slot)
{
    const int r = blockIdx.x;
    const float4 v = reinterpret_cast<const float4*>(X + (size_t)r * LAT_)[threadIdx.x];
    double s = (double)v.x * v.x + (double)v.y * v.y + (double)v.z * v.z + (double)v.w * v.w;
#pragma unroll
    for (int off = 32; off; off >>= 1) s += __shfl_down(s, off, 64);
    if (threadIdx.x == 0) {
        out[r] = (float)s;
        if (loss_slot != nullptr && r == 0) *loss_slot = 0.0f;
    }
}

// ---------------------------------------------------------------------------
// Finalize: reduce 8 partials -> index (float), gather z_q (bf16), loss atomics
// ---------------------------------------------------------------------------
__global__ __launch_bounds__(64) void vq_finalize(
    const float* __restrict__ pval, const int* __restrict__ pidx,
    const float* __restrict__ Z, const float* __restrict__ E,
    unsigned short* __restrict__ zqb, float* __restrict__ out_idx,
    float* __restrict__ loss_slot)
{
    const int row = blockIdx.x;
    __shared__ int sidx;
    if (threadIdx.x == 0) {
        float bv = pval[row * 8]; int bi = pidx[row * 8];
#pragma unroll
        for (int s = 1; s < 8; ++s) {
            const float v = pval[row * 8 + s]; const int ix = pidx[row * 8 + s];
            if (v < bv || (v == bv && ix < bi)) { bv = v; bi = ix; }
        }
        sidx = bi;
        out_idx[row] = (float)bi;
    }
    __syncthreads();
    const int idx = sidx;
    const float4 e = reinterpret_cast<const float4*>(E + (size_t)idx * LAT_)[threadIdx.x];
    const float4 z = reinterpret_cast<const float4*>(Z + (size_t)row * LAT_)[threadIdx.x];
    ushort4 q; q.x = f2bf(e.x); q.y = f2bf(e.y); q.z = f2bf(e.z); q.w = f2bf(e.w);
    reinterpret_cast<ushort4*>(zqb + (size_t)row * LAT_)[threadIdx.x] = q;
    const float dx = z.x - e.x, dy = z.y - e.y, dz = z.z - e.z, dw = z.w - e.w;
    float s = dx * dx + dy * dy + dz * dz + dw * dw;
#pragma unroll
    for (int off = 32; off; off >>= 1) s += __shfl_down(s, off, 64);
    if (threadIdx.x == 0)
        atomicAdd(loss_slot, s * (1.25f / ((float)B_ * (float)LAT_)));
}

// ---------------------------------------------------------------------------
extern "C" void kernel_launch(void* const* d_in, const int* in_sizes, int n_in,
                              void* d_out, int out_size, void* d_ws, size_t ws_size,
                              hipStream_t stream)
{
    const float* x   = (const float*)d_in[0];
    const float* W1  = (const float*)d_in[1];
    const float* b1  = (const float*)d_in[2];
    const float* W2  = (const float*)d_in[3];
    const float* b2  = (const float*)d_in[4];
    const float* W3  = (const float*)d_in[5];
    const float* b3  = (const float*)d_in[6];
    const float* emb = (const float*)d_in[7];
    const float* D1  = (const float*)d_in[8];
    const float* d1  = (const float*)d_in[9];
    const float* D2  = (const float*)d_in[10];
    const float* d2  = (const float*)d_in[11];
    const float* D3  = (const float*)d_in[12];
    const float* d3  = (const float*)d_in[13];
    float* out = (float*)d_out;

    // Workspace map (peak 153 MB < proven 156 MB). 1 MB = 1<<20. Overlays:
    //  [  0, 32M)  h1hi  -> zehi [0,4M), zelo [4,8M) after enc3 -> g1b after vq
    //  [ 32, 64M)  h1lo  -> zqb [32,36M) after enc2 -> g2b after dec1
    //  [ 64, 96M)  xhi[64,80) xlo[80,96) -> h2hi (enc2) -> wt1/wt2/wt3 after enc3
    //  [ 96,128M)  h2lo
    //  [128,136M)  ze fp32
    //  [136,152M)  enc weight splits W1T/W2T/W3T; ehi[144,146) elo[146,148) after enc2
    //  [152,153M)  esq, zsq, pval, pidx
    char* ws = (char*)d_ws;
    const size_t MB = 1u << 20;
    unsigned short* h1hi = (unsigned short*)(ws);
    unsigned short* h1lo = (unsigned short*)(ws + 32 * MB);
    unsigned short* zehi = (unsigned short*)(ws);           // after enc3
    unsigned short* zelo = (unsigned short*)(ws + 4 * MB);  // after enc3
    unsigned short* g1b  = (unsigned short*)(ws);           // after vq
    unsigned short* zqb  = (unsigned short*)(ws + 32 * MB); // after enc2
    unsigned short* g2b  = (unsigned short*)(ws + 32 * MB); // after dec1
    unsigned short* xhi  = (unsigned short*)(ws + 64 * MB);
    unsigned short* xlo  = (unsigned short*)(ws + 80 * MB);
    unsigned short* h2hi = (unsigned short*)(ws + 64 * MB); // after enc1
    unsigned short* h2lo = (unsigned short*)(ws + 96 * MB);
    unsigned short* wt1  = (unsigned short*)(ws + 64 * MB); // after enc3
    unsigned short* wt2  = (unsigned short*)(ws + 65 * MB);
    unsigned short* wt3  = (unsigned short*)(ws + 73 * MB);
    float* ze = (float*)(ws + 128 * MB);
    unsigned short* w1thi = (unsigned short*)(ws + 136 * MB);
    unsigned short* w1tlo = (unsigned short*)(ws + 140 * MB);
    unsigned short* w2thi = (unsigned short*)(ws + 136 * MB); // after enc1
    unsigned short* w2tlo = (unsigned short*)(ws + 144 * MB);
    unsigned short* w3thi = (unsigned short*)(ws + 136 * MB); // after enc2
    unsigned short* w3tlo = (unsigned short*)(ws + 137 * MB);
    unsigned short* ehi   = (unsigned short*)(ws + 144 * MB); // after enc2 (w2tlo dead)
    unsigned short* elo   = (unsigned short*)(ws + 146 * MB);
    float* esq  = (float*)(ws + 152 * MB);
    float* zsq  = (float*)(ws + 152 * MB + 64 * 1024);
    float* pval = (float*)(ws + 152 * MB + 128 * 1024);
    int*   pidx = (int*)  (ws + 152 * MB + 384 * 1024);

    float* loss_slot = out + (size_t)B_ * DIN_;     // d_out[8388608]
    float* out_idx   = loss_slot + 1;               // d_out[8388609..]

    // input + first-layer weight splits
    split_scaled_f16x2<<<(B_ * DIN_ / 4 + 255) / 256, 256, 0, stream>>>(
        x, xhi, xlo, B_ * DIN_ / 4, 1.0f);
    wsplit_transpose<<<dim3(DIN_ / 32, HID_ / 32), dim3(32, 8), 0, stream>>>(W1, w1thi, w1tlo, DIN_, HID_);

    // enc1: x -> h1 (split output), 8-wave 128x128 tile
    gemm_split_f16_w8<1, 1><<<dim3(HID_ / 128, B_ / 128), 512, 0, stream>>>(
        xhi, xlo, w1thi, w1tlo, b1, h1hi, h1lo, nullptr, B_, HID_, DIN_);

    // W2 split (overlays W1T; after enc1)
    wsplit_transpose<<<dim3(HID_ / 32, HID_ / 32), dim3(32, 8), 0, stream>>>(W2, w2thi, w2tlo, HID_, HID_);

    // enc2: h1 -> h2, 8-wave 128x128 tile
    gemm_split_f16_w8<1, 1><<<dim3(HID_ / 128, B_ / 128), 512, 0, stream>>>(
        h1hi, h1lo, w2thi, w2tlo, b2, h2hi, h2lo, nullptr, B_, HID_, HID_);

    // fused codebook prep + W3 split (after enc2)
    emb_prep<<<KC_, 64, 0, stream>>>(emb, esq, ehi, elo, loss_slot);
    wsplit_transpose<<<dim3(HID_ / 32, LAT_ / 32), dim3(32, 8), 0, stream>>>(W3, w3thi, w3tlo, HID_, LAT_);

    // enc3: h2 -> ze fp32 + (zehi, zelo) fused split, no gelu (4-wave, N=256)
    gemm_split_f16<0, 2><<<dim3(LAT_ / 64, B_ / 128), 256, 0, stream>>>(
        h2hi, h2lo, w3thi, w3tlo, b3, zehi, zelo, ze, B_, LAT_, HID_);

    // z row norms
    rowsq_kernel<<<B_, 64, 0, stream>>>(ze, zsq, nullptr);

    // decoder weight prep — one fused dispatch (h2 dead after enc3)
    cast_transpose_w3<<<6656, dim3(32, 8), 0, stream>>>(D1, wt1, D2, wt2, D3, wt3);

    // VQ — MFMA split distances, numpy-fp32-mimicking scores, first-index ties
    vq_argmin_mfma<<<dim3(B_ / 128, 8), 256, 0, stream>>>(
        zehi, zelo, ehi, elo, esq, zsq, pval, pidx);
    vq_finalize<<<B_, 64, 0, stream>>>(pval, pidx, ze, emb, zqb, out_idx, loss_slot);

    // decoder — bf16 MFMA (unchanged numerics)
    gemm_mfma_bf16<1><<<dim3(B_ / 128, HID_ / 128), 256, 0, stream>>>(zqb, wt1, d1, (void*)g1b, B_, HID_, LAT_);
    gemm_mfma_bf16<1><<<dim3(B_ / 128, HID_ / 128), 256, 0, stream>>>(g1b, wt2, d2, (void*)g2b, B_, HID_, HID_);
    gemm_mfma_bf16<0><<<dim3(B_ / 128, DIN_ / 128), 256, 0, stream>>>(g2b, wt3, d3, (void*)out, B_, DIN_, HID_);
}

// Round 6
// 1075.641 us; speedup vs baseline: 1.0539x; 1.0539x over previous
//
#include <hip/hip_runtime.h>
#include <math.h>

// Problem constants
#define B_    8192
#define DIN_  1024
#define HID_  2048
#define LAT_  256
#define KC_   4096   // codebook size

using bfrag8 = __attribute__((ext_vector_type(8))) short;   // 8 bf16 (4 VGPR)
using short8 = __attribute__((ext_vector_type(8))) short;
using half8  = __attribute__((ext_vector_type(8))) _Float16;
using facc4  = __attribute__((ext_vector_type(4))) float;   // MFMA C/D frag

__device__ __forceinline__ unsigned short f2bf(float f) {
    union { float f; unsigned int u; } c; c.f = f;
    unsigned int u = c.u;
    return (unsigned short)((u + 0x7FFFu + ((u >> 16) & 1u)) >> 16);   // RNE
}

__device__ __forceinline__ unsigned short f2h_bits(float f) {
    union { _Float16 h; unsigned short u; } c; c.h = (_Float16)f;
    return c.u;
}

// Async global->LDS, 16B per lane. LDS dest is wave-uniform base + lane*16.
__device__ __forceinline__ void gload16(const unsigned short* g, unsigned short* l) {
    __builtin_amdgcn_global_load_lds(
        (const __attribute__((address_space(1))) void*)(g),
        (__attribute__((address_space(3))) void*)(l), 16, 0, 0);
}

// Bijective XCD-aware block remap (requires nwg % 8 == 0; all grids here
// satisfy it). Dispatch order i -> XCD i%8; remap so each XCD gets a
// CONTIGUOUS chunk of linear block ids -> per-XCD L2 keeps the shared
// A/W k-slices resident. Pure permutation of block->work: outputs identical.
__device__ __forceinline__ unsigned int xcd_swz(unsigned int lin, unsigned int nwg) {
    return (lin & 7u) * (nwg >> 3) + (lin >> 3);
}

// ---------------------------------------------------------------------------
// Encoder GEMM via fp16-split MFMA (Ozaki-style, 2 components, 3 classes).
// 4-wave 128x64 tile, 84 VGPR, 3 blocks/CU — verified r4 sweet spot.
// [r5 lesson: an 8-wave 128x128 variant with launch_bounds(512,4) spilled
//  (VGPR capped at 64 < ~96 needed for the 3 acc sets) and regressed 1.5x.]
// Staging via global_load_lds with pre-swizzled source granule (g^(row&7)):
// LDS contents byte-identical to the verified XOR layout.
// OUT_SPLIT: 0 = f32 only, 1 = f16 split only, 2 = f32 + f16 split.
// ---------------------------------------------------------------------------
template <int GELU, int OUT_SPLIT>
__global__ __launch_bounds__(256, 3) void gemm_split_f16(
    const unsigned short* __restrict__ Ahi, const unsigned short* __restrict__ Alo,
    const unsigned short* __restrict__ WThi, const unsigned short* __restrict__ WTlo,
    const float* __restrict__ bias,
    unsigned short* __restrict__ Chi, unsigned short* __restrict__ Clo,
    float* __restrict__ Cf32,
    int M, int N, int K)
{
    __shared__ __align__(16) unsigned short AsH[128 * 64];   // 16 KB
    __shared__ __align__(16) unsigned short AsL[128 * 64];   // 16 KB
    __shared__ __align__(16) unsigned short WsH[64 * 64];    // 8 KB
    __shared__ __align__(16) unsigned short WsL[64 * 64];    // 8 KB

    const int tid  = threadIdx.x;
    const int wave = tid >> 6;
    const int lane = tid & 63;
    const int wm   = wave & 1;        // wave row (2x2 wave grid)
    const int wn   = wave >> 1;       // wave col
    const int quad = lane >> 4;
    const int ln   = lane & 15;

    // XCD-aware remap: each XCD gets contiguous m-rows (A-slice L2-resident)
    const unsigned int gx  = gridDim.x;
    const unsigned int nl  = xcd_swz(blockIdx.y * gx + blockIdx.x, gx * gridDim.y);
    const int n0 = (int)(nl % gx) * 64;
    const int m0 = (int)(nl / gx) * 128;

    const facc4 fz4 = {0.0f, 0.0f, 0.0f, 0.0f};
    facc4 accA[4][2] = {};    // hi*hi, scale 64, reset every 256 k
    facc4 accB[4][2] = {};    // hi*lo + lo*hi, scale 64*4096, full-K chain
    facc4 master[4][2] = {};  // blocked sum of accA

    for (int k0 = 0; k0 < K; k0 += 64) {
        // stage A tiles 128x64 (hi+lo): dest linear, source granule-swizzled
#pragma unroll
        for (int i = 0; i < 4; ++i) {
            const int idx = i * 256 + tid;
            const int row = idx >> 3;
            const int gs  = (idx & 7) ^ (row & 7);
            const int wb  = i * 256 + (tid & 192);     // wave-uniform granule base
            const size_t src = (size_t)(m0 + row) * K + k0 + gs * 8;
            gload16(&Ahi[src], &AsH[wb * 8]);
            gload16(&Alo[src], &AsL[wb * 8]);
        }
        // stage W tiles 64x64 (hi+lo)
#pragma unroll
        for (int i = 0; i < 2; ++i) {
            const int idx = i * 256 + tid;
            const int row = idx >> 3;
            const int gs  = (idx & 7) ^ (row & 7);
            const int wb  = i * 256 + (tid & 192);
            const size_t src = (size_t)(n0 + row) * K + k0 + gs * 8;
            gload16(&WThi[src], &WsH[wb * 8]);
            gload16(&WTlo[src], &WsL[wb * 8]);
        }
        __syncthreads();
#pragma unroll
        for (int ks = 0; ks < 64; ks += 32) {
            const int gq = (ks >> 3) + quad;      // source granule for this chunk
            half8 aH[4], aL[4], bH[2], bL[2];
#pragma unroll
            for (int f = 0; f < 4; ++f) {
                const int row = wm * 64 + f * 16 + ln;
                const int off = row * 64 + ((gq ^ (ln & 7)) << 3);
                aH[f] = *reinterpret_cast<const half8*>(&AsH[off]);
                aL[f] = *reinterpret_cast<const half8*>(&AsL[off]);
            }
#pragma unroll
            for (int f = 0; f < 2; ++f) {
                const int row = wn * 32 + f * 16 + ln;
                const int off = row * 64 + ((gq ^ (ln & 7)) << 3);
                bH[f] = *reinterpret_cast<const half8*>(&WsH[off]);
                bL[f] = *reinterpret_cast<const half8*>(&WsL[off]);
            }
#pragma unroll
            for (int fm = 0; fm < 4; ++fm)
#pragma unroll
                for (int fn = 0; fn < 2; ++fn)
                    accA[fm][fn] = __builtin_amdgcn_mfma_f32_16x16x32_f16(
                        aH[fm], bH[fn], accA[fm][fn], 0, 0, 0);
#pragma unroll
            for (int fm = 0; fm < 4; ++fm)
#pragma unroll
                for (int fn = 0; fn < 2; ++fn)
                    accB[fm][fn] = __builtin_amdgcn_mfma_f32_16x16x32_f16(
                        aH[fm], bL[fn], accB[fm][fn], 0, 0, 0);
#pragma unroll
            for (int fm = 0; fm < 4; ++fm)
#pragma unroll
                for (int fn = 0; fn < 2; ++fn)
                    accB[fm][fn] = __builtin_amdgcn_mfma_f32_16x16x32_f16(
                        aL[fm], bH[fn], accB[fm][fn], 0, 0, 0);
        }
        __syncthreads();
        if ((k0 & 192) == 192) {            // end of each 256-k block: promote
#pragma unroll
            for (int fm = 0; fm < 4; ++fm)
#pragma unroll
                for (int fn = 0; fn < 2; ++fn) {
                    master[fm][fn] += accA[fm][fn];
                    accA[fm][fn] = fz4;
                }
        }
    }

    const double SC_HI = 0.015625;               // 1/64
    const double SC_LO = 3.814697265625e-06;     // 1/(64*4096)
#pragma unroll
    for (int fn = 0; fn < 2; ++fn) {
        const int col = n0 + wn * 32 + fn * 16 + ln;
        const double bb = (double)bias[col];
#pragma unroll
        for (int fm = 0; fm < 4; ++fm) {
            const int rbase = m0 + wm * 64 + fm * 16 + quad * 4;
#pragma unroll
            for (int r = 0; r < 4; ++r) {
                double v = (double)master[fm][fn][r] * SC_HI
                         + (double)accB[fm][fn][r] * SC_LO + bb;
                if (GELU) v = 0.5 * v * (1.0 + erf(v * 0.70710678118654752440));
                const float hf = (float)v;
                if (OUT_SPLIT == 1 || OUT_SPLIT == 2) {
                    const _Float16 hi = (_Float16)hf;
                    const float lo = (hf - (float)hi) * 4096.0f;
                    union { _Float16 h; unsigned short u; } c1, c2;
                    c1.h = hi; c2.h = (_Float16)lo;
                    Chi[(size_t)(rbase + r) * N + col] = c1.u;
                    Clo[(size_t)(rbase + r) * N + col] = c2.u;
                }
                if (OUT_SPLIT == 0 || OUT_SPLIT == 2) {
                    Cf32[(size_t)(rbase + r) * N + col] = hf;
                }
            }
        }
    }
}

// ---------------------------------------------------------------------------
// Split fp32 -> (hi, lo*4096) fp16 pair, with pre-scale (power of two, exact).
// ---------------------------------------------------------------------------
__global__ __launch_bounds__(256) void split_scaled_f16x2(
    const float* __restrict__ X, unsigned short* __restrict__ Xhi,
    unsigned short* __restrict__ Xlo, int n4, float scale)
{
    const int i = blockIdx.x * 256 + threadIdx.x;
    if (i >= n4) return;
    const float4 v = reinterpret_cast<const float4*>(X)[i];
    ushort4 h, l;
    {
        const float s = v.x * scale;
        _Float16 a = (_Float16)s; h.x = f2h_bits((float)a); l.x = f2h_bits((s - (float)a) * 4096.0f);
    }
    {
        const float s = v.y * scale;
        _Float16 a = (_Float16)s; h.y = f2h_bits((float)a); l.y = f2h_bits((s - (float)a) * 4096.0f);
    }
    {
        const float s = v.z * scale;
        _Float16 a = (_Float16)s; h.z = f2h_bits((float)a); l.z = f2h_bits((s - (float)a) * 4096.0f);
    }
    {
        const float s = v.w * scale;
        _Float16 a = (_Float16)s; h.w = f2h_bits((float)a); l.w = f2h_bits((s - (float)a) * 4096.0f);
    }
    reinterpret_cast<ushort4*>(Xhi)[i] = h;
    reinterpret_cast<ushort4*>(Xlo)[i] = l;
}

// ---------------------------------------------------------------------------
// Fused codebook prep: esq + f16 split (x2^16) + loss zero. (verified r4)
// ---------------------------------------------------------------------------
__global__ __launch_bounds__(64) void emb_prep(
    const float* __restrict__ E, float* __restrict__ esq,
    unsigned short* __restrict__ Ehi, unsigned short* __restrict__ Elo,
    float* __restrict__ loss_slot)
{
    const int r = blockIdx.x;
    const float4 v = reinterpret_cast<const float4*>(E + (size_t)r * LAT_)[threadIdx.x];
    ushort4 h, l;
    {
        const float s = v.x * 65536.0f;
        _Float16 a = (_Float16)s; h.x = f2h_bits((float)a); l.x = f2h_bits((s - (float)a) * 4096.0f);
    }
    {
        const float s = v.y * 65536.0f;
        _Float16 a = (_Float16)s; h.y = f2h_bits((float)a); l.y = f2h_bits((s - (float)a) * 4096.0f);
    }
    {
        const float s = v.z * 65536.0f;
        _Float16 a = (_Float16)s; h.z = f2h_bits((float)a); l.z = f2h_bits((s - (float)a) * 4096.0f);
    }
    {
        const float s = v.w * 65536.0f;
        _Float16 a = (_Float16)s; h.w = f2h_bits((float)a); l.w = f2h_bits((s - (float)a) * 4096.0f);
    }
    reinterpret_cast<ushort4*>(Ehi + (size_t)r * LAT_)[threadIdx.x] = h;
    reinterpret_cast<ushort4*>(Elo + (size_t)r * LAT_)[threadIdx.x] = l;
    double s = (double)v.x * v.x + (double)v.y * v.y + (double)v.z * v.z + (double)v.w * v.w;
#pragma unroll
    for (int off = 32; off; off >>= 1) s += __shfl_down(s, off, 64);
    if (threadIdx.x == 0) {
        esq[r] = (float)s;
        if (r == 0) *loss_slot = 0.0f;
    }
}

// ---------------------------------------------------------------------------
// Weight prep: W [K,N] fp32 -> WThi/WTlo [N,K] f16 of (W*64, residual*4096).
// ---------------------------------------------------------------------------
__global__ __launch_bounds__(256) void wsplit_transpose(
    const float* __restrict__ W, unsigned short* __restrict__ WThi,
    unsigned short* __restrict__ WTlo, int K, int N)
{
    __shared__ float t[32][33];
    const int k0 = blockIdx.x * 32;
    const int n0 = blockIdx.y * 32;
    const int x = threadIdx.x;
    const int y = threadIdx.y;
#pragma unroll
    for (int i = 0; i < 4; ++i)
        t[y + i * 8][x] = W[(size_t)(k0 + y + i * 8) * N + n0 + x];
    __syncthreads();
#pragma unroll
    for (int i = 0; i < 4; ++i) {
        const float w = t[x][y + i * 8] * 64.0f;
        const _Float16 hi = (_Float16)w;
        const float lo = (w - (float)hi) * 4096.0f;
        WThi[(size_t)(n0 + y + i * 8) * K + k0 + x] = f2h_bits((float)hi);
        WTlo[(size_t)(n0 + y + i * 8) * K + k0 + x] = f2h_bits(lo);
    }
}

// ---------------------------------------------------------------------------
// VQ distance + argmin via fp16-split MFMA (verified r4 numerics).
// + XCD swizzle: each XCD owns one 512-entry codebook split (E hi+lo 512 KB
//   -> L2-resident per XCD). + occupancy 3 blocks/CU (50 KB LDS x3 <= 160).
// ---------------------------------------------------------------------------
__global__ __launch_bounds__(256, 3) void vq_argmin_mfma(
    const unsigned short* __restrict__ Zhi, const unsigned short* __restrict__ Zlo,
    const unsigned short* __restrict__ Ehi, const unsigned short* __restrict__ Elo,
    const float* __restrict__ esq, const float* __restrict__ zsq,
    float* __restrict__ pval, int* __restrict__ pidx)
{
    __shared__ __align__(16) unsigned short ZsH[128 * 64];   // 16 KB
    __shared__ __align__(16) unsigned short ZsL[128 * 64];   // 16 KB
    __shared__ __align__(16) unsigned short EsH[64 * 64];    // 8 KB
    __shared__ __align__(16) unsigned short EsL[64 * 64];    // 8 KB
    __shared__ float rbv[128][2];
    __shared__ int   rbi[128][2];

    const int tid  = threadIdx.x;
    const int wave = tid >> 6;
    const int lane = tid & 63;
    const int wm   = wave & 1;
    const int wn   = wave >> 1;
    const int quad = lane >> 4;
    const int ln   = lane & 15;

    // XCD remap: grid (64, 8) -> nl/64 = split, nl%64 = m-block
    const unsigned int nl = xcd_swz(blockIdx.y * 64 + blockIdx.x, 512);
    const int m0    = (int)(nl & 63u) * 128;
    const int split = (int)(nl >> 6);

    float zsqv[4][4];
#pragma unroll
    for (int fm = 0; fm < 4; ++fm) {
        const float4 q = *reinterpret_cast<const float4*>(
            &zsq[m0 + wm * 64 + fm * 16 + quad * 4]);
        zsqv[fm][0] = q.x; zsqv[fm][1] = q.y; zsqv[fm][2] = q.z; zsqv[fm][3] = q.w;
    }

    float bestv[4][4];
    int   besti[4][4];
#pragma unroll
    for (int a = 0; a < 4; ++a)
#pragma unroll
        for (int b = 0; b < 4; ++b) { bestv[a][b] = 3.4e38f; besti[a][b] = 0; }

    for (int nt = 0; nt < 8; ++nt) {
        const int n0 = split * 512 + nt * 64;
        facc4 accA[4][2] = {};
        facc4 accB[4][2] = {};
        for (int k0 = 0; k0 < 256; k0 += 64) {
            __syncthreads();
#pragma unroll
            for (int i = 0; i < 4; ++i) {
                const int idx = i * 256 + tid;
                const int row = idx >> 3;
                const int gs  = (idx & 7) ^ (row & 7);
                const int wb  = i * 256 + (tid & 192);
                const size_t src = (size_t)(m0 + row) * LAT_ + k0 + gs * 8;
                gload16(&Zhi[src], &ZsH[wb * 8]);
                gload16(&Zlo[src], &ZsL[wb * 8]);
            }
#pragma unroll
            for (int i = 0; i < 2; ++i) {
                const int idx = i * 256 + tid;
                const int row = idx >> 3;
                const int gs  = (idx & 7) ^ (row & 7);
                const int wb  = i * 256 + (tid & 192);
                const size_t src = (size_t)(n0 + row) * LAT_ + k0 + gs * 8;
                gload16(&Ehi[src], &EsH[wb * 8]);
                gload16(&Elo[src], &EsL[wb * 8]);
            }
            __syncthreads();
#pragma unroll
            for (int ks = 0; ks < 64; ks += 32) {
                const int gq = (ks >> 3) + quad;
                half8 aH[4], aL[4], bH[2], bL[2];
#pragma unroll
                for (int f = 0; f < 4; ++f) {
                    const int row = wm * 64 + f * 16 + ln;
                    const int off = row * 64 + ((gq ^ (ln & 7)) << 3);
                    aH[f] = *reinterpret_cast<const half8*>(&ZsH[off]);
                    aL[f] = *reinterpret_cast<const half8*>(&ZsL[off]);
                }
#pragma unroll
                for (int f = 0; f < 2; ++f) {
                    const int row = wn * 32 + f * 16 + ln;
                    const int off = row * 64 + ((gq ^ (ln & 7)) << 3);
                    bH[f] = *reinterpret_cast<const half8*>(&EsH[off]);
                    bL[f] = *reinterpret_cast<const half8*>(&EsL[off]);
                }
#pragma unroll
                for (int fm = 0; fm < 4; ++fm)
#pragma unroll
                    for (int fn = 0; fn < 2; ++fn)
                        accA[fm][fn] = __builtin_amdgcn_mfma_f32_16x16x32_f16(
                            aH[fm], bH[fn], accA[fm][fn], 0, 0, 0);
#pragma unroll
                for (int fm = 0; fm < 4; ++fm)
#pragma unroll
                    for (int fn = 0; fn < 2; ++fn)
                        accB[fm][fn] = __builtin_amdgcn_mfma_f32_16x16x32_f16(
                            aH[fm], bL[fn], accB[fm][fn], 0, 0, 0);
#pragma unroll
                for (int fm = 0; fm < 4; ++fm)
#pragma unroll
                    for (int fn = 0; fn < 2; ++fn)
                        accB[fm][fn] = __builtin_amdgcn_mfma_f32_16x16x32_f16(
                            aL[fm], bH[fn], accB[fm][fn], 0, 0, 0);
            }
        }
#pragma unroll
        for (int fm = 0; fm < 4; ++fm)
#pragma unroll
            for (int fn = 0; fn < 2; ++fn) {
                const int n = n0 + wn * 32 + fn * 16 + ln;
                const float es = esq[n];
#pragma unroll
                for (int r = 0; r < 4; ++r) {
                    const float pa = accA[fm][fn][r] * 0x1p-15f;   // exact
                    const float pb = accB[fm][fn][r] * 0x1p-27f;   // exact
                    const float t2m = pa + pb;
                    const float sc = (zsqv[fm][r] + es) - t2m;
                    if (sc < bestv[fm][r]) { bestv[fm][r] = sc; besti[fm][r] = n; }
                }
            }
    }

#pragma unroll
    for (int fm = 0; fm < 4; ++fm)
#pragma unroll
        for (int r = 0; r < 4; ++r) {
            float v0 = bestv[fm][r]; int i0 = besti[fm][r];
#pragma unroll
            for (int mask = 1; mask < 16; mask <<= 1) {
                const float v2 = __shfl_xor(v0, mask, 64);
                const int   i2 = __shfl_xor(i0, mask, 64);
                if (v2 < v0 || (v2 == v0 && i2 < i0)) { v0 = v2; i0 = i2; }
            }
            bestv[fm][r] = v0; besti[fm][r] = i0;
        }

    if (ln == 0) {
#pragma unroll
        for (int fm = 0; fm < 4; ++fm)
#pragma unroll
            for (int r = 0; r < 4; ++r) {
                const int rl = wm * 64 + fm * 16 + quad * 4 + r;
                rbv[rl][wn] = bestv[fm][r];
                rbi[rl][wn] = besti[fm][r];
            }
    }
    __syncthreads();
    if (tid < 128) {
        float bv = rbv[tid][0]; int bi = rbi[tid][0];
        const float v = rbv[tid][1]; const int ix = rbi[tid][1];
        if (v < bv || (v == bv && ix < bi)) { bv = v; bi = ix; }
        pval[(size_t)(m0 + tid) * 8 + split] = bv;
        pidx[(m0 + tid) * 8 + split] = bi;
    }
}

// ---------------------------------------------------------------------------
// Decoder GEMM: bf16 MFMA 16x16x32 (verified numerics) + XCD swizzle.
// ---------------------------------------------------------------------------
template <int OUT_BF16>
__global__ __launch_bounds__(256) void gemm_mfma_bf16(
    const unsigned short* __restrict__ A,
    const unsigned short* __restrict__ WT,
    const float* __restrict__ bias,
    void* __restrict__ Cout,
    int M, int N, int K)
{
    __shared__ __align__(16) unsigned short As[128 * 64];   // [m][k], 16 KB
    __shared__ __align__(16) unsigned short Bs[128 * 64];   // [n][k], 16 KB

    const int tid  = threadIdx.x;
    const int wave = tid >> 6;
    const int lane = tid & 63;
    const int wm   = wave & 1;
    const int wn   = wave >> 1;
    const int quad = lane >> 4;
    const int ln   = lane & 15;

    const unsigned int gx  = gridDim.x;
    const unsigned int nl  = xcd_swz(blockIdx.y * gx + blockIdx.x, gx * gridDim.y);
    const int m0 = (int)(nl % gx) * 128;
    const int n0 = (int)(nl / gx) * 128;

    facc4 acc[4][4] = {};

    for (int k0 = 0; k0 < K; k0 += 64) {
#pragma unroll
        for (int i = 0; i < 4; ++i) {
            const int idx = i * 256 + tid;
            const int row = idx >> 3;
            const int c8  = (idx & 7) * 8;
            const int wb  = i * 256 + (tid & 192);
            gload16(&A[(size_t)(m0 + row) * K + k0 + c8], &As[wb * 8]);
            gload16(&WT[(size_t)(n0 + row) * K + k0 + c8], &Bs[wb * 8]);
        }
        __syncthreads();
#pragma unroll
        for (int ks = 0; ks < 64; ks += 32) {
            bfrag8 am[4], bn[4];
#pragma unroll
            for (int f = 0; f < 4; ++f) {
                am[f] = *reinterpret_cast<const bfrag8*>(
                    &As[(wm * 64 + f * 16 + ln) * 64 + ks + quad * 8]);
                bn[f] = *reinterpret_cast<const bfrag8*>(
                    &Bs[(wn * 64 + f * 16 + ln) * 64 + ks + quad * 8]);
            }
#pragma unroll
            for (int fm = 0; fm < 4; ++fm)
#pragma unroll
                for (int fn = 0; fn < 4; ++fn)
                    acc[fm][fn] = __builtin_amdgcn_mfma_f32_16x16x32_bf16(
                        am[fm], bn[fn], acc[fm][fn], 0, 0, 0);
        }
        __syncthreads();
    }

#pragma unroll
    for (int fn = 0; fn < 4; ++fn) {
        const int col = n0 + wn * 64 + fn * 16 + ln;
        const float bf = bias[col];
#pragma unroll
        for (int fm = 0; fm < 4; ++fm) {
            const int rbase = m0 + wm * 64 + fm * 16 + quad * 4;
#pragma unroll
            for (int r = 0; r < 4; ++r) {
                float v = acc[fm][fn][r] + bf;
                if (OUT_BF16) {
                    v = 0.5f * v * (1.0f + erff(v * 0.70710678118654752440f));
                    ((unsigned short*)Cout)[(size_t)(rbase + r) * N + col] = f2bf(v);
                } else {
                    ((float*)Cout)[(size_t)(rbase + r) * N + col] = v;
                }
            }
        }
    }
}

// ---------------------------------------------------------------------------
// Fused cast+transpose for the three decoder weights (bit-identical per-tile
// math to the verified cast_transpose_w; one dispatch instead of three).
// ---------------------------------------------------------------------------
__global__ __launch_bounds__(256) void cast_transpose_w3(
    const float* __restrict__ D1w, unsigned short* __restrict__ wt1,
    const float* __restrict__ D2w, unsigned short* __restrict__ wt2,
    const float* __restrict__ D3w, unsigned short* __restrict__ wt3)
{
    const int bid = blockIdx.x;
    const float* W; unsigned short* WT; int K, N, kt, nt;
    if (bid < 512)        { W = D1w; WT = wt1; K = LAT_; N = HID_; kt = bid & 7;  nt = bid >> 3; }
    else if (bid < 4608)  { const int l = bid - 512;  W = D2w; WT = wt2; K = HID_; N = HID_; kt = l & 63; nt = l >> 6; }
    else                  { const int l = bid - 4608; W = D3w; WT = wt3; K = HID_; N = DIN_; kt = l & 63; nt = l >> 6; }

    __shared__ float t[32][33];
    const int k0 = kt * 32;
    const int n0 = nt * 32;
    const int x = threadIdx.x;
    const int y = threadIdx.y;
#pragma unroll
    for (int i = 0; i < 4; ++i)
        t[y + i * 8][x] = W[(size_t)(k0 + y + i * 8) * N + n0 + x];
    __syncthreads();
#pragma unroll
    for (int i = 0; i < 4; ++i)
        WT[(size_t)(n0 + y + i * 8) * K + k0 + x] = f2bf(t[x][y + i * 8]);
}

// ---------------------------------------------------------------------------
// rowsq[r] = fp32( fp64 sum of X[r,:].^2 ), rows of width LAT_=256.
// ---------------------------------------------------------------------------
__global__ __launch_bounds__(64) void rowsq_kernel(
    const float* __restrict__ X, float* __restrict__ out,
    float* __restrict__ loss_slot)
{
    const int r = blockIdx.x;
    const float4 v = reinterpret_cast<const float4*>(X + (size_t)r * LAT_)[threadIdx.x];
    double s = (double)v.x * v.x + (double)v.y * v.y + (double)v.z * v.z + (double)v.w * v.w;
#pragma unroll
    for (int off = 32; off; off >>= 1) s += __shfl_down(s, off, 64);
    if (threadIdx.x == 0) {
        out[r] = (float)s;
        if (loss_slot != nullptr && r == 0) *loss_slot = 0.0f;
    }
}

// ---------------------------------------------------------------------------
// Finalize: reduce 8 partials -> index (float), gather z_q (bf16), loss atomics
// ---------------------------------------------------------------------------
__global__ __launch_bounds__(64) void vq_finalize(
    const float* __restrict__ pval, const int* __restrict__ pidx,
    const float* __restrict__ Z, const float* __restrict__ E,
    unsigned short* __restrict__ zqb, float* __restrict__ out_idx,
    float* __restrict__ loss_slot)
{
    const int row = blockIdx.x;
    __shared__ int sidx;
    if (threadIdx.x == 0) {
        float bv = pval[row * 8]; int bi = pidx[row * 8];
#pragma unroll
        for (int s = 1; s < 8; ++s) {
            const float v = pval[row * 8 + s]; const int ix = pidx[row * 8 + s];
            if (v < bv || (v == bv && ix < bi)) { bv = v; bi = ix; }
        }
        sidx = bi;
        out_idx[row] = (float)bi;
    }
    __syncthreads();
    const int idx = sidx;
    const float4 e = reinterpret_cast<const float4*>(E + (size_t)idx * LAT_)[threadIdx.x];
    const float4 z = reinterpret_cast<const float4*>(Z + (size_t)row * LAT_)[threadIdx.x];
    ushort4 q; q.x = f2bf(e.x); q.y = f2bf(e.y); q.z = f2bf(e.z); q.w = f2bf(e.w);
    reinterpret_cast<ushort4*>(zqb + (size_t)row * LAT_)[threadIdx.x] = q;
    const float dx = z.x - e.x, dy = z.y - e.y, dz = z.z - e.z, dw = z.w - e.w;
    float s = dx * dx + dy * dy + dz * dz + dw * dw;
#pragma unroll
    for (int off = 32; off; off >>= 1) s += __shfl_down(s, off, 64);
    if (threadIdx.x == 0)
        atomicAdd(loss_slot, s * (1.25f / ((float)B_ * (float)LAT_)));
}

// ---------------------------------------------------------------------------
extern "C" void kernel_launch(void* const* d_in, const int* in_sizes, int n_in,
                              void* d_out, int out_size, void* d_ws, size_t ws_size,
                              hipStream_t stream)
{
    const float* x   = (const float*)d_in[0];
    const float* W1  = (const float*)d_in[1];
    const float* b1  = (const float*)d_in[2];
    const float* W2  = (const float*)d_in[3];
    const float* b2  = (const float*)d_in[4];
    const float* W3  = (const float*)d_in[5];
    const float* b3  = (const float*)d_in[6];
    const float* emb = (const float*)d_in[7];
    const float* D1  = (const float*)d_in[8];
    const float* d1  = (const float*)d_in[9];
    const float* D2  = (const float*)d_in[10];
    const float* d2  = (const float*)d_in[11];
    const float* D3  = (const float*)d_in[12];
    const float* d3  = (const float*)d_in[13];
    float* out = (float*)d_out;

    // Workspace map (peak 153 MB < proven 156 MB). 1 MB = 1<<20. Overlays:
    //  [  0, 32M)  h1hi  -> zehi [0,4M), zelo [4,8M) after enc3 -> g1b after vq
    //  [ 32, 64M)  h1lo  -> zqb [32,36M) after enc2 -> g2b after dec1
    //  [ 64, 96M)  xhi[64,80) xlo[80,96) -> h2hi (enc2) -> wt1/wt2/wt3 after enc3
    //  [ 96,128M)  h2lo
    //  [128,136M)  ze fp32
    //  [136,152M)  enc weight splits W1T/W2T/W3T; ehi[144,146) elo[146,148) after enc2
    //  [152,153M)  esq, zsq, pval, pidx
    char* ws = (char*)d_ws;
    const size_t MB = 1u << 20;
    unsigned short* h1hi = (unsigned short*)(ws);
    unsigned short* h1lo = (unsigned short*)(ws + 32 * MB);
    unsigned short* zehi = (unsigned short*)(ws);           // after enc3
    unsigned short* zelo = (unsigned short*)(ws + 4 * MB);  // after enc3
    unsigned short* g1b  = (unsigned short*)(ws);           // after vq
    unsigned short* zqb  = (unsigned short*)(ws + 32 * MB); // after enc2
    unsigned short* g2b  = (unsigned short*)(ws + 32 * MB); // after dec1
    unsigned short* xhi  = (unsigned short*)(ws + 64 * MB);
    unsigned short* xlo  = (unsigned short*)(ws + 80 * MB);
    unsigned short* h2hi = (unsigned short*)(ws + 64 * MB); // after enc1
    unsigned short* h2lo = (unsigned short*)(ws + 96 * MB);
    unsigned short* wt1  = (unsigned short*)(ws + 64 * MB); // after enc3
    unsigned short* wt2  = (unsigned short*)(ws + 65 * MB);
    unsigned short* wt3  = (unsigned short*)(ws + 73 * MB);
    float* ze = (float*)(ws + 128 * MB);
    unsigned short* w1thi = (unsigned short*)(ws + 136 * MB);
    unsigned short* w1tlo = (unsigned short*)(ws + 140 * MB);
    unsigned short* w2thi = (unsigned short*)(ws + 136 * MB); // after enc1
    unsigned short* w2tlo = (unsigned short*)(ws + 144 * MB);
    unsigned short* w3thi = (unsigned short*)(ws + 136 * MB); // after enc2
    unsigned short* w3tlo = (unsigned short*)(ws + 137 * MB);
    unsigned short* ehi   = (unsigned short*)(ws + 144 * MB); // after enc2 (w2tlo dead)
    unsigned short* elo   = (unsigned short*)(ws + 146 * MB);
    float* esq  = (float*)(ws + 152 * MB);
    float* zsq  = (float*)(ws + 152 * MB + 64 * 1024);
    float* pval = (float*)(ws + 152 * MB + 128 * 1024);
    int*   pidx = (int*)  (ws + 152 * MB + 384 * 1024);

    float* loss_slot = out + (size_t)B_ * DIN_;     // d_out[8388608]
    float* out_idx   = loss_slot + 1;               // d_out[8388609..]

    // input + first-layer weight splits
    split_scaled_f16x2<<<(B_ * DIN_ / 4 + 255) / 256, 256, 0, stream>>>(
        x, xhi, xlo, B_ * DIN_ / 4, 1.0f);
    wsplit_transpose<<<dim3(DIN_ / 32, HID_ / 32), dim3(32, 8), 0, stream>>>(W1, w1thi, w1tlo, DIN_, HID_);

    // enc1: x -> h1 (split output), verified 4-wave kernel
    gemm_split_f16<1, 1><<<dim3(HID_ / 64, B_ / 128), 256, 0, stream>>>(
        xhi, xlo, w1thi, w1tlo, b1, h1hi, h1lo, nullptr, B_, HID_, DIN_);

    // W2 split (overlays W1T; after enc1)
    wsplit_transpose<<<dim3(HID_ / 32, HID_ / 32), dim3(32, 8), 0, stream>>>(W2, w2thi, w2tlo, HID_, HID_);

    // enc2: h1 -> h2
    gemm_split_f16<1, 1><<<dim3(HID_ / 64, B_ / 128), 256, 0, stream>>>(
        h1hi, h1lo, w2thi, w2tlo, b2, h2hi, h2lo, nullptr, B_, HID_, HID_);

    // fused codebook prep + W3 split (after enc2)
    emb_prep<<<KC_, 64, 0, stream>>>(emb, esq, ehi, elo, loss_slot);
    wsplit_transpose<<<dim3(HID_ / 32, LAT_ / 32), dim3(32, 8), 0, stream>>>(W3, w3thi, w3tlo, HID_, LAT_);

    // enc3: h2 -> ze fp32 + (zehi, zelo) fused split, no gelu
    gemm_split_f16<0, 2><<<dim3(LAT_ / 64, B_ / 128), 256, 0, stream>>>(
        h2hi, h2lo, w3thi, w3tlo, b3, zehi, zelo, ze, B_, LAT_, HID_);

    // z row norms
    rowsq_kernel<<<B_, 64, 0, stream>>>(ze, zsq, nullptr);

    // decoder weight prep — one fused dispatch (h2 dead after enc3)
    cast_transpose_w3<<<6656, dim3(32, 8), 0, stream>>>(D1, wt1, D2, wt2, D3, wt3);

    // VQ — MFMA split distances, numpy-fp32-mimicking scores, first-index ties
    vq_argmin_mfma<<<dim3(B_ / 128, 8), 256, 0, stream>>>(
        zehi, zelo, ehi, elo, esq, zsq, pval, pidx);
    vq_finalize<<<B_, 64, 0, stream>>>(pval, pidx, ze, emb, zqb, out_idx, loss_slot);

    // decoder — bf16 MFMA (unchanged numerics)
    gemm_mfma_bf16<1><<<dim3(B_ / 128, HID_ / 128), 256, 0, stream>>>(zqb, wt1, d1, (void*)g1b, B_, HID_, LAT_);
    gemm_mfma_bf16<1><<<dim3(B_ / 128, HID_ / 128), 256, 0, stream>>>(g1b, wt2, d2, (void*)g2b, B_, HID_, HID_);
    gemm_mfma_bf16<0><<<dim3(B_ / 128, DIN_ / 128), 256, 0, stream>>>(g2b, wt3, d3, (void*)out, B_, DIN_, HID_);
}

// Round 7
// 994.715 us; speedup vs baseline: 1.1397x; 1.0814x over previous
//
#include <hip/hip_runtime.h>
#include <math.h>

// Problem constants
#define B_    8192
#define DIN_  1024
#define HID_  2048
#define LAT_  256
#define KC_   4096   // codebook size

using bfrag8 = __attribute__((ext_vector_type(8))) short;   // 8 bf16 (4 VGPR)
using short8 = __attribute__((ext_vector_type(8))) short;
using half8  = __attribute__((ext_vector_type(8))) _Float16;
using facc4  = __attribute__((ext_vector_type(4))) float;   // MFMA C/D frag

__device__ __forceinline__ unsigned short f2bf(float f) {
    union { float f; unsigned int u; } c; c.f = f;
    unsigned int u = c.u;
    return (unsigned short)((u + 0x7FFFu + ((u >> 16) & 1u)) >> 16);   // RNE
}

__device__ __forceinline__ unsigned short f2h_bits(float f) {
    union { _Float16 h; unsigned short u; } c; c.h = (_Float16)f;
    return c.u;
}

// Async global->LDS, 16B per lane. LDS dest is wave-uniform base + lane*16.
__device__ __forceinline__ void gload16(const unsigned short* g, unsigned short* l) {
    __builtin_amdgcn_global_load_lds(
        (const __attribute__((address_space(1))) void*)(g),
        (__attribute__((address_space(3))) void*)(l), 16, 0, 0);
}

// ---------------------------------------------------------------------------
// Encoder GEMM via fp16-split MFMA (Ozaki-style, 2 components, 3 classes).
// 4-wave 128x64 tile, 84 VGPR, 3 blocks/CU — verified r4 sweet spot.
// [r5 lesson: 8-wave 128x128 w/ launch_bounds(512,4) spills -> 1.5x regress.]
// [r6 lesson: XCD-chunked block swizzle RAISES L2-miss traffic (313->465MB)
//  and doesn't move time — default dispatch order already optimal here.]
// Staging via global_load_lds with pre-swizzled source granule (g^(row&7)):
// LDS contents byte-identical to the verified XOR layout.
// OUT_SPLIT: 0 = f32 only, 1 = f16 split only, 2 = f32 + f16 split.
// ---------------------------------------------------------------------------
template <int GELU, int OUT_SPLIT>
__global__ __launch_bounds__(256, 3) void gemm_split_f16(
    const unsigned short* __restrict__ Ahi, const unsigned short* __restrict__ Alo,
    const unsigned short* __restrict__ WThi, const unsigned short* __restrict__ WTlo,
    const float* __restrict__ bias,
    unsigned short* __restrict__ Chi, unsigned short* __restrict__ Clo,
    float* __restrict__ Cf32,
    int M, int N, int K)
{
    __shared__ __align__(16) unsigned short AsH[128 * 64];   // 16 KB
    __shared__ __align__(16) unsigned short AsL[128 * 64];   // 16 KB
    __shared__ __align__(16) unsigned short WsH[64 * 64];    // 8 KB
    __shared__ __align__(16) unsigned short WsL[64 * 64];    // 8 KB

    const int tid  = threadIdx.x;
    const int wave = tid >> 6;
    const int lane = tid & 63;
    const int wm   = wave & 1;        // wave row (2x2 wave grid)
    const int wn   = wave >> 1;       // wave col
    const int quad = lane >> 4;
    const int ln   = lane & 15;
    const int n0 = blockIdx.x * 64;   // x = n-tile: consecutive blocks share A tile
    const int m0 = blockIdx.y * 128;

    const facc4 fz4 = {0.0f, 0.0f, 0.0f, 0.0f};
    facc4 accA[4][2] = {};    // hi*hi, scale 64, reset every 256 k
    facc4 accB[4][2] = {};    // hi*lo + lo*hi, scale 64*4096, full-K chain
    facc4 master[4][2] = {};  // blocked sum of accA

    for (int k0 = 0; k0 < K; k0 += 64) {
        // stage A tiles 128x64 (hi+lo): dest linear, source granule-swizzled
#pragma unroll
        for (int i = 0; i < 4; ++i) {
            const int idx = i * 256 + tid;
            const int row = idx >> 3;
            const int gs  = (idx & 7) ^ (row & 7);
            const int wb  = i * 256 + (tid & 192);     // wave-uniform granule base
            const size_t src = (size_t)(m0 + row) * K + k0 + gs * 8;
            gload16(&Ahi[src], &AsH[wb * 8]);
            gload16(&Alo[src], &AsL[wb * 8]);
        }
        // stage W tiles 64x64 (hi+lo)
#pragma unroll
        for (int i = 0; i < 2; ++i) {
            const int idx = i * 256 + tid;
            const int row = idx >> 3;
            const int gs  = (idx & 7) ^ (row & 7);
            const int wb  = i * 256 + (tid & 192);
            const size_t src = (size_t)(n0 + row) * K + k0 + gs * 8;
            gload16(&WThi[src], &WsH[wb * 8]);
            gload16(&WTlo[src], &WsL[wb * 8]);
        }
        __syncthreads();
#pragma unroll
        for (int ks = 0; ks < 64; ks += 32) {
            const int gq = (ks >> 3) + quad;      // source granule for this chunk
            half8 aH[4], aL[4], bH[2], bL[2];
#pragma unroll
            for (int f = 0; f < 4; ++f) {
                const int row = wm * 64 + f * 16 + ln;
                const int off = row * 64 + ((gq ^ (ln & 7)) << 3);
                aH[f] = *reinterpret_cast<const half8*>(&AsH[off]);
                aL[f] = *reinterpret_cast<const half8*>(&AsL[off]);
            }
#pragma unroll
            for (int f = 0; f < 2; ++f) {
                const int row = wn * 32 + f * 16 + ln;
                const int off = row * 64 + ((gq ^ (ln & 7)) << 3);
                bH[f] = *reinterpret_cast<const half8*>(&WsH[off]);
                bL[f] = *reinterpret_cast<const half8*>(&WsL[off]);
            }
#pragma unroll
            for (int fm = 0; fm < 4; ++fm)
#pragma unroll
                for (int fn = 0; fn < 2; ++fn)
                    accA[fm][fn] = __builtin_amdgcn_mfma_f32_16x16x32_f16(
                        aH[fm], bH[fn], accA[fm][fn], 0, 0, 0);
#pragma unroll
            for (int fm = 0; fm < 4; ++fm)
#pragma unroll
                for (int fn = 0; fn < 2; ++fn)
                    accB[fm][fn] = __builtin_amdgcn_mfma_f32_16x16x32_f16(
                        aH[fm], bL[fn], accB[fm][fn], 0, 0, 0);
#pragma unroll
            for (int fm = 0; fm < 4; ++fm)
#pragma unroll
                for (int fn = 0; fn < 2; ++fn)
                    accB[fm][fn] = __builtin_amdgcn_mfma_f32_16x16x32_f16(
                        aL[fm], bH[fn], accB[fm][fn], 0, 0, 0);
        }
        __syncthreads();
        if ((k0 & 192) == 192) {            // end of each 256-k block: promote
#pragma unroll
            for (int fm = 0; fm < 4; ++fm)
#pragma unroll
                for (int fn = 0; fn < 2; ++fn) {
                    master[fm][fn] += accA[fm][fn];
                    accA[fm][fn] = fz4;
                }
        }
    }

    const double SC_HI = 0.015625;               // 1/64
    const double SC_LO = 3.814697265625e-06;     // 1/(64*4096)
#pragma unroll
    for (int fn = 0; fn < 2; ++fn) {
        const int col = n0 + wn * 32 + fn * 16 + ln;
        const double bb = (double)bias[col];
#pragma unroll
        for (int fm = 0; fm < 4; ++fm) {
            const int rbase = m0 + wm * 64 + fm * 16 + quad * 4;
#pragma unroll
            for (int r = 0; r < 4; ++r) {
                double v = (double)master[fm][fn][r] * SC_HI
                         + (double)accB[fm][fn][r] * SC_LO + bb;
                if (GELU) v = 0.5 * v * (1.0 + erf(v * 0.70710678118654752440));
                const float hf = (float)v;
                if (OUT_SPLIT == 1 || OUT_SPLIT == 2) {
                    const _Float16 hi = (_Float16)hf;
                    const float lo = (hf - (float)hi) * 4096.0f;
                    union { _Float16 h; unsigned short u; } c1, c2;
                    c1.h = hi; c2.h = (_Float16)lo;
                    Chi[(size_t)(rbase + r) * N + col] = c1.u;
                    Clo[(size_t)(rbase + r) * N + col] = c2.u;
                }
                if (OUT_SPLIT == 0 || OUT_SPLIT == 2) {
                    Cf32[(size_t)(rbase + r) * N + col] = hf;
                }
            }
        }
    }
}

// ---------------------------------------------------------------------------
// Fused input prep: x split + W1/W2/W3 split-transpose, one dispatch.
// Per-thread math identical to the verified split_scaled_f16x2 /
// wsplit_transpose kernels (block-range decode only) -> bit-identical.
//   [    0,  8192): x  split (8192 x 256 threads over 2M float4)
//   [ 8192, 10240): W1 [1024,2048] -> 32x64 tiles
//   [10240, 14336): W2 [2048,2048] -> 64x64 tiles
//   [14336, 14848): W3 [2048, 256] -> 64x8  tiles
// ---------------------------------------------------------------------------
__global__ __launch_bounds__(256) void prep_all(
    const float* __restrict__ X, unsigned short* __restrict__ Xhi,
    unsigned short* __restrict__ Xlo,
    const float* __restrict__ W1w, unsigned short* __restrict__ w1thi,
    unsigned short* __restrict__ w1tlo,
    const float* __restrict__ W2w, unsigned short* __restrict__ w2thi,
    unsigned short* __restrict__ w2tlo,
    const float* __restrict__ W3w, unsigned short* __restrict__ w3thi,
    unsigned short* __restrict__ w3tlo)
{
    const int bid = blockIdx.x;
    const int tid = threadIdx.x;

    if (bid < 8192) {
        // x split (scale 1.0)
        const int i = bid * 256 + tid;
        const float4 v = reinterpret_cast<const float4*>(X)[i];
        ushort4 h, l;
        {
            _Float16 a = (_Float16)v.x; h.x = f2h_bits((float)a); l.x = f2h_bits((v.x - (float)a) * 4096.0f);
        }
        {
            _Float16 a = (_Float16)v.y; h.y = f2h_bits((float)a); l.y = f2h_bits((v.y - (float)a) * 4096.0f);
        }
        {
            _Float16 a = (_Float16)v.z; h.z = f2h_bits((float)a); l.z = f2h_bits((v.z - (float)a) * 4096.0f);
        }
        {
            _Float16 a = (_Float16)v.w; h.w = f2h_bits((float)a); l.w = f2h_bits((v.w - (float)a) * 4096.0f);
        }
        reinterpret_cast<ushort4*>(Xhi)[i] = h;
        reinterpret_cast<ushort4*>(Xlo)[i] = l;
        return;
    }

    // weight split-transpose (identical math to wsplit_transpose)
    const float* W; unsigned short* WThi; unsigned short* WTlo; int K, N, kt, nt;
    if (bid < 10240)      { const int l = bid - 8192;  W = W1w; WThi = w1thi; WTlo = w1tlo; K = DIN_; N = HID_; kt = l & 31; nt = l >> 5; }
    else if (bid < 14336) { const int l = bid - 10240; W = W2w; WThi = w2thi; WTlo = w2tlo; K = HID_; N = HID_; kt = l & 63; nt = l >> 6; }
    else                  { const int l = bid - 14336; W = W3w; WThi = w3thi; WTlo = w3tlo; K = HID_; N = LAT_; kt = l & 63; nt = l >> 6; }

    __shared__ float t[32][33];
    const int k0 = kt * 32;
    const int n0 = nt * 32;
    const int x = tid & 31;
    const int y = tid >> 5;
#pragma unroll
    for (int i = 0; i < 4; ++i)
        t[y + i * 8][x] = W[(size_t)(k0 + y + i * 8) * N + n0 + x];
    __syncthreads();
#pragma unroll
    for (int i = 0; i < 4; ++i) {
        const float w = t[x][y + i * 8] * 64.0f;
        const _Float16 hi = (_Float16)w;
        const float lo = (w - (float)hi) * 4096.0f;
        WThi[(size_t)(n0 + y + i * 8) * K + k0 + x] = f2h_bits((float)hi);
        WTlo[(size_t)(n0 + y + i * 8) * K + k0 + x] = f2h_bits(lo);
    }
}

// ---------------------------------------------------------------------------
// Fused codebook prep: esq + f16 split (x2^16) + loss zero. (verified r4)
// ---------------------------------------------------------------------------
__global__ __launch_bounds__(64) void emb_prep(
    const float* __restrict__ E, float* __restrict__ esq,
    unsigned short* __restrict__ Ehi, unsigned short* __restrict__ Elo,
    float* __restrict__ loss_slot)
{
    const int r = blockIdx.x;
    const float4 v = reinterpret_cast<const float4*>(E + (size_t)r * LAT_)[threadIdx.x];
    ushort4 h, l;
    {
        const float s = v.x * 65536.0f;
        _Float16 a = (_Float16)s; h.x = f2h_bits((float)a); l.x = f2h_bits((s - (float)a) * 4096.0f);
    }
    {
        const float s = v.y * 65536.0f;
        _Float16 a = (_Float16)s; h.y = f2h_bits((float)a); l.y = f2h_bits((s - (float)a) * 4096.0f);
    }
    {
        const float s = v.z * 65536.0f;
        _Float16 a = (_Float16)s; h.z = f2h_bits((float)a); l.z = f2h_bits((s - (float)a) * 4096.0f);
    }
    {
        const float s = v.w * 65536.0f;
        _Float16 a = (_Float16)s; h.w = f2h_bits((float)a); l.w = f2h_bits((s - (float)a) * 4096.0f);
    }
    reinterpret_cast<ushort4*>(Ehi + (size_t)r * LAT_)[threadIdx.x] = h;
    reinterpret_cast<ushort4*>(Elo + (size_t)r * LAT_)[threadIdx.x] = l;
    double s = (double)v.x * v.x + (double)v.y * v.y + (double)v.z * v.z + (double)v.w * v.w;
#pragma unroll
    for (int off = 32; off; off >>= 1) s += __shfl_down(s, off, 64);
    if (threadIdx.x == 0) {
        esq[r] = (float)s;
        if (r == 0) *loss_slot = 0.0f;
    }
}

// ---------------------------------------------------------------------------
// VQ distance + argmin via fp16-split MFMA (verified r4 config: lb(256,2),
// direct blockIdx mapping — r6 swizzle+occ3 regressed, reverted).
// ---------------------------------------------------------------------------
__global__ __launch_bounds__(256, 2) void vq_argmin_mfma(
    const unsigned short* __restrict__ Zhi, const unsigned short* __restrict__ Zlo,
    const unsigned short* __restrict__ Ehi, const unsigned short* __restrict__ Elo,
    const float* __restrict__ esq, const float* __restrict__ zsq,
    float* __restrict__ pval, int* __restrict__ pidx)
{
    __shared__ __align__(16) unsigned short ZsH[128 * 64];   // 16 KB
    __shared__ __align__(16) unsigned short ZsL[128 * 64];   // 16 KB
    __shared__ __align__(16) unsigned short EsH[64 * 64];    // 8 KB
    __shared__ __align__(16) unsigned short EsL[64 * 64];    // 8 KB
    __shared__ float rbv[128][2];
    __shared__ int   rbi[128][2];

    const int tid  = threadIdx.x;
    const int wave = tid >> 6;
    const int lane = tid & 63;
    const int wm   = wave & 1;
    const int wn   = wave >> 1;
    const int quad = lane >> 4;
    const int ln   = lane & 15;
    const int m0    = blockIdx.x * 128;
    const int split = blockIdx.y;

    float zsqv[4][4];
#pragma unroll
    for (int fm = 0; fm < 4; ++fm) {
        const float4 q = *reinterpret_cast<const float4*>(
            &zsq[m0 + wm * 64 + fm * 16 + quad * 4]);
        zsqv[fm][0] = q.x; zsqv[fm][1] = q.y; zsqv[fm][2] = q.z; zsqv[fm][3] = q.w;
    }

    float bestv[4][4];
    int   besti[4][4];
#pragma unroll
    for (int a = 0; a < 4; ++a)
#pragma unroll
        for (int b = 0; b < 4; ++b) { bestv[a][b] = 3.4e38f; besti[a][b] = 0; }

    for (int nt = 0; nt < 8; ++nt) {
        const int n0 = split * 512 + nt * 64;
        facc4 accA[4][2] = {};
        facc4 accB[4][2] = {};
        for (int k0 = 0; k0 < 256; k0 += 64) {
            __syncthreads();
#pragma unroll
            for (int i = 0; i < 4; ++i) {
                const int idx = i * 256 + tid;
                const int row = idx >> 3;
                const int gs  = (idx & 7) ^ (row & 7);
                const int wb  = i * 256 + (tid & 192);
                const size_t src = (size_t)(m0 + row) * LAT_ + k0 + gs * 8;
                gload16(&Zhi[src], &ZsH[wb * 8]);
                gload16(&Zlo[src], &ZsL[wb * 8]);
            }
#pragma unroll
            for (int i = 0; i < 2; ++i) {
                const int idx = i * 256 + tid;
                const int row = idx >> 3;
                const int gs  = (idx & 7) ^ (row & 7);
                const int wb  = i * 256 + (tid & 192);
                const size_t src = (size_t)(n0 + row) * LAT_ + k0 + gs * 8;
                gload16(&Ehi[src], &EsH[wb * 8]);
                gload16(&Elo[src], &EsL[wb * 8]);
            }
            __syncthreads();
#pragma unroll
            for (int ks = 0; ks < 64; ks += 32) {
                const int gq = (ks >> 3) + quad;
                half8 aH[4], aL[4], bH[2], bL[2];
#pragma unroll
                for (int f = 0; f < 4; ++f) {
                    const int row = wm * 64 + f * 16 + ln;
                    const int off = row * 64 + ((gq ^ (ln & 7)) << 3);
                    aH[f] = *reinterpret_cast<const half8*>(&ZsH[off]);
                    aL[f] = *reinterpret_cast<const half8*>(&ZsL[off]);
                }
#pragma unroll
                for (int f = 0; f < 2; ++f) {
                    const int row = wn * 32 + f * 16 + ln;
                    const int off = row * 64 + ((gq ^ (ln & 7)) << 3);
                    bH[f] = *reinterpret_cast<const half8*>(&EsH[off]);
                    bL[f] = *reinterpret_cast<const half8*>(&EsL[off]);
                }
#pragma unroll
                for (int fm = 0; fm < 4; ++fm)
#pragma unroll
                    for (int fn = 0; fn < 2; ++fn)
                        accA[fm][fn] = __builtin_amdgcn_mfma_f32_16x16x32_f16(
                            aH[fm], bH[fn], accA[fm][fn], 0, 0, 0);
#pragma unroll
                for (int fm = 0; fm < 4; ++fm)
#pragma unroll
                    for (int fn = 0; fn < 2; ++fn)
                        accB[fm][fn] = __builtin_amdgcn_mfma_f32_16x16x32_f16(
                            aH[fm], bL[fn], accB[fm][fn], 0, 0, 0);
#pragma unroll
                for (int fm = 0; fm < 4; ++fm)
#pragma unroll
                    for (int fn = 0; fn < 2; ++fn)
                        accB[fm][fn] = __builtin_amdgcn_mfma_f32_16x16x32_f16(
                            aL[fm], bH[fn], accB[fm][fn], 0, 0, 0);
            }
        }
#pragma unroll
        for (int fm = 0; fm < 4; ++fm)
#pragma unroll
            for (int fn = 0; fn < 2; ++fn) {
                const int n = n0 + wn * 32 + fn * 16 + ln;
                const float es = esq[n];
#pragma unroll
                for (int r = 0; r < 4; ++r) {
                    const float pa = accA[fm][fn][r] * 0x1p-15f;   // exact
                    const float pb = accB[fm][fn][r] * 0x1p-27f;   // exact
                    const float t2m = pa + pb;
                    const float sc = (zsqv[fm][r] + es) - t2m;
                    if (sc < bestv[fm][r]) { bestv[fm][r] = sc; besti[fm][r] = n; }
                }
            }
    }

#pragma unroll
    for (int fm = 0; fm < 4; ++fm)
#pragma unroll
        for (int r = 0; r < 4; ++r) {
            float v0 = bestv[fm][r]; int i0 = besti[fm][r];
#pragma unroll
            for (int mask = 1; mask < 16; mask <<= 1) {
                const float v2 = __shfl_xor(v0, mask, 64);
                const int   i2 = __shfl_xor(i0, mask, 64);
                if (v2 < v0 || (v2 == v0 && i2 < i0)) { v0 = v2; i0 = i2; }
            }
            bestv[fm][r] = v0; besti[fm][r] = i0;
        }

    if (ln == 0) {
#pragma unroll
        for (int fm = 0; fm < 4; ++fm)
#pragma unroll
            for (int r = 0; r < 4; ++r) {
                const int rl = wm * 64 + fm * 16 + quad * 4 + r;
                rbv[rl][wn] = bestv[fm][r];
                rbi[rl][wn] = besti[fm][r];
            }
    }
    __syncthreads();
    if (tid < 128) {
        float bv = rbv[tid][0]; int bi = rbi[tid][0];
        const float v = rbv[tid][1]; const int ix = rbi[tid][1];
        if (v < bv || (v == bv && ix < bi)) { bv = v; bi = ix; }
        pval[(size_t)(m0 + tid) * 8 + split] = bv;
        pidx[(m0 + tid) * 8 + split] = bi;
    }
}

// ---------------------------------------------------------------------------
// Decoder GEMM: bf16 MFMA 16x16x32 (verified r4 config, no swizzle)
// ---------------------------------------------------------------------------
template <int OUT_BF16>
__global__ __launch_bounds__(256) void gemm_mfma_bf16(
    const unsigned short* __restrict__ A,
    const unsigned short* __restrict__ WT,
    const float* __restrict__ bias,
    void* __restrict__ Cout,
    int M, int N, int K)
{
    __shared__ __align__(16) unsigned short As[128 * 64];   // [m][k], 16 KB
    __shared__ __align__(16) unsigned short Bs[128 * 64];   // [n][k], 16 KB

    const int tid  = threadIdx.x;
    const int wave = tid >> 6;
    const int lane = tid & 63;
    const int wm   = wave & 1;
    const int wn   = wave >> 1;
    const int quad = lane >> 4;
    const int ln   = lane & 15;
    const int m0 = blockIdx.x * 128;
    const int n0 = blockIdx.y * 128;

    facc4 acc[4][4] = {};

    for (int k0 = 0; k0 < K; k0 += 64) {
#pragma unroll
        for (int i = 0; i < 4; ++i) {
            const int idx = i * 256 + tid;
            const int row = idx >> 3;
            const int c8  = (idx & 7) * 8;
            const int wb  = i * 256 + (tid & 192);
            gload16(&A[(size_t)(m0 + row) * K + k0 + c8], &As[wb * 8]);
            gload16(&WT[(size_t)(n0 + row) * K + k0 + c8], &Bs[wb * 8]);
        }
        __syncthreads();
#pragma unroll
        for (int ks = 0; ks < 64; ks += 32) {
            bfrag8 am[4], bn[4];
#pragma unroll
            for (int f = 0; f < 4; ++f) {
                am[f] = *reinterpret_cast<const bfrag8*>(
                    &As[(wm * 64 + f * 16 + ln) * 64 + ks + quad * 8]);
                bn[f] = *reinterpret_cast<const bfrag8*>(
                    &Bs[(wn * 64 + f * 16 + ln) * 64 + ks + quad * 8]);
            }
#pragma unroll
            for (int fm = 0; fm < 4; ++fm)
#pragma unroll
                for (int fn = 0; fn < 4; ++fn)
                    acc[fm][fn] = __builtin_amdgcn_mfma_f32_16x16x32_bf16(
                        am[fm], bn[fn], acc[fm][fn], 0, 0, 0);
        }
        __syncthreads();
    }

#pragma unroll
    for (int fn = 0; fn < 4; ++fn) {
        const int col = n0 + wn * 64 + fn * 16 + ln;
        const float bf = bias[col];
#pragma unroll
        for (int fm = 0; fm < 4; ++fm) {
            const int rbase = m0 + wm * 64 + fm * 16 + quad * 4;
#pragma unroll
            for (int r = 0; r < 4; ++r) {
                float v = acc[fm][fn][r] + bf;
                if (OUT_BF16) {
                    v = 0.5f * v * (1.0f + erff(v * 0.70710678118654752440f));
                    ((unsigned short*)Cout)[(size_t)(rbase + r) * N + col] = f2bf(v);
                } else {
                    ((float*)Cout)[(size_t)(rbase + r) * N + col] = v;
                }
            }
        }
    }
}

// ---------------------------------------------------------------------------
// Fused cast+transpose for the three decoder weights (verified r4/r5).
// ---------------------------------------------------------------------------
__global__ __launch_bounds__(256) void cast_transpose_w3(
    const float* __restrict__ D1w, unsigned short* __restrict__ wt1,
    const float* __restrict__ D2w, unsigned short* __restrict__ wt2,
    const float* __restrict__ D3w, unsigned short* __restrict__ wt3)
{
    const int bid = blockIdx.x;
    const float* W; unsigned short* WT; int K, N, kt, nt;
    if (bid < 512)        { W = D1w; WT = wt1; K = LAT_; N = HID_; kt = bid & 7;  nt = bid >> 3; }
    else if (bid < 4608)  { const int l = bid - 512;  W = D2w; WT = wt2; K = HID_; N = HID_; kt = l & 63; nt = l >> 6; }
    else                  { const int l = bid - 4608; W = D3w; WT = wt3; K = HID_; N = DIN_; kt = l & 63; nt = l >> 6; }

    __shared__ float t[32][33];
    const int k0 = kt * 32;
    const int n0 = nt * 32;
    const int x = threadIdx.x;
    const int y = threadIdx.y;
#pragma unroll
    for (int i = 0; i < 4; ++i)
        t[y + i * 8][x] = W[(size_t)(k0 + y + i * 8) * N + n0 + x];
    __syncthreads();
#pragma unroll
    for (int i = 0; i < 4; ++i)
        WT[(size_t)(n0 + y + i * 8) * K + k0 + x] = f2bf(t[x][y + i * 8]);
}

// ---------------------------------------------------------------------------
// rowsq[r] = fp32( fp64 sum of X[r,:].^2 ), rows of width LAT_=256.
// ---------------------------------------------------------------------------
__global__ __launch_bounds__(64) void rowsq_kernel(
    const float* __restrict__ X, float* __restrict__ out,
    float* __restrict__ loss_slot)
{
    const int r = blockIdx.x;
    const float4 v = reinterpret_cast<const float4*>(X + (size_t)r * LAT_)[threadIdx.x];
    double s = (double)v.x * v.x + (double)v.y * v.y + (double)v.z * v.z + (double)v.w * v.w;
#pragma unroll
    for (int off = 32; off; off >>= 1) s += __shfl_down(s, off, 64);
    if (threadIdx.x == 0) {
        out[r] = (float)s;
        if (loss_slot != nullptr && r == 0) *loss_slot = 0.0f;
    }
}

// ---------------------------------------------------------------------------
// Finalize: reduce 8 partials -> index (float), gather z_q (bf16), loss atomics
// ---------------------------------------------------------------------------
__global__ __launch_bounds__(64) void vq_finalize(
    const float* __restrict__ pval, const int* __restrict__ pidx,
    const float* __restrict__ Z, const float* __restrict__ E,
    unsigned short* __restrict__ zqb, float* __restrict__ out_idx,
    float* __restrict__ loss_slot)
{
    const int row = blockIdx.x;
    __shared__ int sidx;
    if (threadIdx.x == 0) {
        float bv = pval[row * 8]; int bi = pidx[row * 8];
#pragma unroll
        for (int s = 1; s < 8; ++s) {
            const float v = pval[row * 8 + s]; const int ix = pidx[row * 8 + s];
            if (v < bv || (v == bv && ix < bi)) { bv = v; bi = ix; }
        }
        sidx = bi;
        out_idx[row] = (float)bi;
    }
    __syncthreads();
    const int idx = sidx;
    const float4 e = reinterpret_cast<const float4*>(E + (size_t)idx * LAT_)[threadIdx.x];
    const float4 z = reinterpret_cast<const float4*>(Z + (size_t)row * LAT_)[threadIdx.x];
    ushort4 q; q.x = f2bf(e.x); q.y = f2bf(e.y); q.z = f2bf(e.z); q.w = f2bf(e.w);
    reinterpret_cast<ushort4*>(zqb + (size_t)row * LAT_)[threadIdx.x] = q;
    const float dx = z.x - e.x, dy = z.y - e.y, dz = z.z - e.z, dw = z.w - e.w;
    float s = dx * dx + dy * dy + dz * dz + dw * dw;
#pragma unroll
    for (int off = 32; off; off >>= 1) s += __shfl_down(s, off, 64);
    if (threadIdx.x == 0)
        atomicAdd(loss_slot, s * (1.25f / ((float)B_ * (float)LAT_)));
}

// ---------------------------------------------------------------------------
extern "C" void kernel_launch(void* const* d_in, const int* in_sizes, int n_in,
                              void* d_out, int out_size, void* d_ws, size_t ws_size,
                              hipStream_t stream)
{
    const float* x   = (const float*)d_in[0];
    const float* W1  = (const float*)d_in[1];
    const float* b1  = (const float*)d_in[2];
    const float* W2  = (const float*)d_in[3];
    const float* b2  = (const float*)d_in[4];
    const float* W3  = (const float*)d_in[5];
    const float* b3  = (const float*)d_in[6];
    const float* emb = (const float*)d_in[7];
    const float* D1  = (const float*)d_in[8];
    const float* d1  = (const float*)d_in[9];
    const float* D2  = (const float*)d_in[10];
    const float* d2  = (const float*)d_in[11];
    const float* D3  = (const float*)d_in[12];
    const float* d3  = (const float*)d_in[13];
    float* out = (float*)d_out;

    // Workspace map (peak ~154.6 MB < proven 156 MB). 1 MB = 1<<20. Overlays:
    //  [  0, 64M)  h1hi [0,32) h1lo [32,64)
    //              -> zehi [0,4), zelo [4,8) after enc3; zqb [32,36) after vq
    //              -> g1b [0,32) after vq; g2b [32,64) after dec1
    //  [ 64, 96M)  xhi [64,80) xlo [80,96)  -> h2hi after enc1
    //              -> wt1 [64,65) wt2 [65,73) wt3 [73,77) after enc3
    //  [ 96,128M)  w1t [96,104) (dead after enc1) -> h2lo (enc2 output)
    //  [128,136M)  ze fp32
    //  [136,152M)  w2t hi [136,144) lo [144,152)
    //              -> ehi [144,146) elo [146,148) after enc2
    //  [152,154M)  w3t hi [152,153) lo [153,154)
    //  [154M.. )   esq, zsq, pval, pidx (~640 KB)
    char* ws = (char*)d_ws;
    const size_t MB = 1u << 20;
    unsigned short* h1hi = (unsigned short*)(ws);
    unsigned short* h1lo = (unsigned short*)(ws + 32 * MB);
    unsigned short* zehi = (unsigned short*)(ws);           // after enc3
    unsigned short* zelo = (unsigned short*)(ws + 4 * MB);  // after enc3
    unsigned short* g1b  = (unsigned short*)(ws);           // after vq
    unsigned short* zqb  = (unsigned short*)(ws + 32 * MB); // after vq
    unsigned short* g2b  = (unsigned short*)(ws + 32 * MB); // after dec1
    unsigned short* xhi  = (unsigned short*)(ws + 64 * MB);
    unsigned short* xlo  = (unsigned short*)(ws + 80 * MB);
    unsigned short* h2hi = (unsigned short*)(ws + 64 * MB); // after enc1
    unsigned short* h2lo = (unsigned short*)(ws + 96 * MB); // after enc1 (w1t dead)
    unsigned short* wt1  = (unsigned short*)(ws + 64 * MB); // after enc3
    unsigned short* wt2  = (unsigned short*)(ws + 65 * MB);
    unsigned short* wt3  = (unsigned short*)(ws + 73 * MB);
    unsigned short* w1thi = (unsigned short*)(ws + 96 * MB);
    unsigned short* w1tlo = (unsigned short*)(ws + 100 * MB);
    float* ze = (float*)(ws + 128 * MB);
    unsigned short* w2thi = (unsigned short*)(ws + 136 * MB);
    unsigned short* w2tlo = (unsigned short*)(ws + 144 * MB);
    unsigned short* ehi   = (unsigned short*)(ws + 144 * MB); // after enc2 (w2tlo dead)
    unsigned short* elo   = (unsigned short*)(ws + 146 * MB);
    unsigned short* w3thi = (unsigned short*)(ws + 152 * MB);
    unsigned short* w3tlo = (unsigned short*)(ws + 153 * MB);
    float* esq  = (float*)(ws + 154 * MB);
    float* zsq  = (float*)(ws + 154 * MB + 64 * 1024);
    float* pval = (float*)(ws + 154 * MB + 128 * 1024);
    int*   pidx = (int*)  (ws + 154 * MB + 384 * 1024);

    float* loss_slot = out + (size_t)B_ * DIN_;     // d_out[8388608]
    float* out_idx   = loss_slot + 1;               // d_out[8388609..]

    // all input prep in one dispatch (x split + W1/W2/W3 split-transpose)
    prep_all<<<14848, 256, 0, stream>>>(
        x, xhi, xlo, W1, w1thi, w1tlo, W2, w2thi, w2tlo, W3, w3thi, w3tlo);

    // enc1: x -> h1 (split output)
    gemm_split_f16<1, 1><<<dim3(HID_ / 64, B_ / 128), 256, 0, stream>>>(
        xhi, xlo, w1thi, w1tlo, b1, h1hi, h1lo, nullptr, B_, HID_, DIN_);

    // enc2: h1 -> h2 (h2hi over dead xsplit, h2lo over dead w1t)
    gemm_split_f16<1, 1><<<dim3(HID_ / 64, B_ / 128), 256, 0, stream>>>(
        h1hi, h1lo, w2thi, w2tlo, b2, h2hi, h2lo, nullptr, B_, HID_, HID_);

    // fused codebook prep (esq + split x2^16 + loss zero; over dead w2tlo)
    emb_prep<<<KC_, 64, 0, stream>>>(emb, esq, ehi, elo, loss_slot);

    // enc3: h2 -> ze fp32 + (zehi, zelo) fused split, no gelu
    gemm_split_f16<0, 2><<<dim3(LAT_ / 64, B_ / 128), 256, 0, stream>>>(
        h2hi, h2lo, w3thi, w3tlo, b3, zehi, zelo, ze, B_, LAT_, HID_);

    // z row norms
    rowsq_kernel<<<B_, 64, 0, stream>>>(ze, zsq, nullptr);

    // decoder weight prep — one fused dispatch (h2 dead after enc3)
    cast_transpose_w3<<<6656, dim3(32, 8), 0, stream>>>(D1, wt1, D2, wt2, D3, wt3);

    // VQ — MFMA split distances, numpy-fp32-mimicking scores, first-index ties
    vq_argmin_mfma<<<dim3(B_ / 128, 8), 256, 0, stream>>>(
        zehi, zelo, ehi, elo, esq, zsq, pval, pidx);
    vq_finalize<<<B_, 64, 0, stream>>>(pval, pidx, ze, emb, zqb, out_idx, loss_slot);

    // decoder — bf16 MFMA (unchanged numerics)
    gemm_mfma_bf16<1><<<dim3(B_ / 128, HID_ / 128), 256, 0, stream>>>(zqb, wt1, d1, (void*)g1b, B_, HID_, LAT_);
    gemm_mfma_bf16<1><<<dim3(B_ / 128, HID_ / 128), 256, 0, stream>>>(g1b, wt2, d2, (void*)g2b, B_, HID_, HID_);
    gemm_mfma_bf16<0><<<dim3(B_ / 128, DIN_ / 128), 256, 0, stream>>>(g2b, wt3, d3, (void*)out, B_, DIN_, HID_);
}